// Round 4
// baseline (1719.891 us; speedup 1.0000x reference)
//
#include <hip/hip_runtime.h>
#include <hip/hip_bf16.h>

using bf16 = __hip_bfloat16;
typedef __bf16 bf16x8v __attribute__((ext_vector_type(8)));
typedef __bf16 bf16x4v __attribute__((ext_vector_type(4)));
typedef float f32x4v __attribute__((ext_vector_type(4)));

#define EMBED 1024
#define FF_DIM 4096
#define NTOK 4096          // BATCH * SEQ
#define SEQL 2048
#define HD 64
#define WBAND 46           // ceil(sqrt(2048))
#define LN_EPS 1e-5f

// async global->LDS, 16B per lane. LDS dest must be wave-uniform base +
// lane*16B (m104/m108); our staging layout satisfies this (tid*8 bf16 elems).
__device__ __forceinline__ void gload16(const bf16* g, bf16* l)
{
  __builtin_amdgcn_global_load_lds(
      (const __attribute__((address_space(1))) void*)g,
      (__attribute__((address_space(3))) void*)l, 16, 0, 0);
}

// ---------------------------------------------------------------------------
// Input-dtype detection (robust): fp32 tensors have random mantissa bits in
// the low halfword (sane-bf16-exponent rate ~20%); bf16 tensors have a real
// N(0,1) bf16 there (rate ~100%). flag: 1 = bf16 inputs, 0 = fp32 inputs.
// ---------------------------------------------------------------------------
__global__ __launch_bounds__(256) void detect_dtype(
    const unsigned int* __restrict__ xw, int* __restrict__ flag)
{
  __shared__ int votes[256];
  int v = 0;
#pragma unroll
  for (int j = 0; j < 4; j++) {
    unsigned int w = xw[1 + threadIdx.x * 4 + j];
    unsigned int e = (w >> 7) & 0xFFu;          // low halfword's bf16 exponent
    v += (e == 0u || (e >= 0x58u && e <= 0x88u)) ? 1 : 0;
  }
  votes[threadIdx.x] = v;
  __syncthreads();
  if (threadIdx.x == 0) {
    int s = 0;
    for (int i = 0; i < 256; i++) s += votes[i];
    *flag = (s > 512) ? 1 : 0;
  }
}

// generic param cast -> bf16 internal copy (biases / LN gains), flag-branched
__global__ __launch_bounds__(256) void cast_param(
    const void* __restrict__ src, bf16* __restrict__ dst, int n,
    const int* __restrict__ dflag)
{
  const int is_bf16 = *dflag;
  for (int i = blockIdx.x * 256 + threadIdx.x; i < n; i += gridDim.x * 256)
    dst[i] = is_bf16 ? ((const bf16*)src)[i] : (bf16)(((const float*)src)[i]);
}

// x -> fp32 residual stream + bf16 activation copy, flag-branched
__global__ __launch_bounds__(256) void cast_in(
    const void* __restrict__ x, float* __restrict__ xf,
    bf16* __restrict__ xb, int n, const int* __restrict__ dflag)
{
  const int is_bf16 = *dflag;
  const int i = blockIdx.x * 256 + threadIdx.x;
  if (i < n) {
    float v = is_bf16 ? (float)((const bf16*)x)[i] : ((const float*)x)[i];
    xf[i] = v;
    xb[i] = (bf16)v;
  }
}

// ---------------------------------------------------------------------------
// NT GEMM core: C[128 x BN block] = A[M,K] @ W[N,K]^T + bias[N].
// A bf16 internal; W raw (fp32 or bf16 per flag, converted at commit time).
// ROUND-4 STRUCTURE (T3 2-phase, single barrier per K-step):
//   prologue: stage tile0 into buf0; barrier
//   iter t:   issue tile t+1 loads (A via global_load_lds width=16 -> buf^1,
//             B into regs) | ds_read + MFMA tile t from buf | commit B into
//             buf^1 (vmcnt wait lands here, hidden under the MFMAs above) |
//             ONE __syncthreads (drains gload_lds + makes B visible)
// vs round-3: removes one barrier per step and A's reg->LDS round-trip
// (round-3 profile: MfmaUtil 11.5%, occupancy 21% -> still latency-bound).
// Verified MFMA layouts (m89/m91): A/B-frag row=lane&15,k=(lane>>4)*8+j;
// C/D col=lane&15, row=(lane>>4)*4+reg.  EPI: 1 = relu.
// ---------------------------------------------------------------------------
template<int EPI, int BN>
__device__ __forceinline__ void gemm_core(
    const bf16* __restrict__ A, const void* __restrict__ Wp, size_t woff,
    const bf16* __restrict__ bias, bf16* __restrict__ C,
    int N, int K, int is_bf16, int row0, int col0)
{
  __shared__ __align__(16) bf16 lA[2][128 * 32];
  __shared__ __align__(16) bf16 lB[2][BN * 32];
  constexpr int NJ = BN / 32;

  const int tid  = threadIdx.x;
  const int wave = tid >> 6;
  const int lane = tid & 63;
  const int wr0  = (wave >> 1) * 64;
  const int wc0  = (wave & 1) * (BN / 2);

  f32x4v acc[4][NJ];
#pragma unroll
  for (int i = 0; i < 4; i++)
#pragma unroll
    for (int j = 0; j < NJ; j++) acc[i][j] = (f32x4v){0.f, 0.f, 0.f, 0.f};

  // A staging: row = wave*16 + lane/4 (+64 second 16B), kchunk=(lane&3)*8.
  // LDS elem offset = tid*8 -> per-wave linear (base + lane*16B): gload_lds ok.
  const int srow = wave * 16 + (lane >> 2);
  const int skc  = (lane & 3) * 8;
  const bf16* Ag = A + (size_t)(row0 + srow) * K + skc;
  // B staging: BN=128 mirrors A (2 vectors); BN=64: row=tid/4 (1 vector)
  size_t bidx;
  if constexpr (BN == 128) bidx = woff + (size_t)(col0 + srow) * K + skc;
  else                     bidx = woff + (size_t)(col0 + (tid >> 2)) * K + (size_t)(tid & 3) * 8;
  const int lo = tid * 8;

  const int fr = lane & 15;
  const int q8 = (lane >> 4) * 8;

  bf16x8v nb0, nb1;
  f32x4v  g0, g1, g2, g3;

  auto issue = [&](int k0, int buf) {
    gload16(Ag + k0, &lA[buf][lo]);
    gload16(Ag + (size_t)64 * K + k0, &lA[buf][lo + 2048]);
    if (is_bf16) {
      const bf16* Wb = (const bf16*)Wp + bidx + k0;
      nb0 = *reinterpret_cast<const bf16x8v*>(Wb);
      if constexpr (BN == 128)
        nb1 = *reinterpret_cast<const bf16x8v*>(Wb + (size_t)64 * K);
    } else {
      const float* Wf = (const float*)Wp + bidx + k0;
      g0 = *reinterpret_cast<const f32x4v*>(Wf);
      g1 = *reinterpret_cast<const f32x4v*>(Wf + 4);
      if constexpr (BN == 128) {
        g2 = *reinterpret_cast<const f32x4v*>(Wf + (size_t)64 * K);
        g3 = *reinterpret_cast<const f32x4v*>(Wf + (size_t)64 * K + 4);
      }
    }
  };

  auto commitB = [&](int buf) {
    bf16x8v w0, w1;
    if (is_bf16) {
      w0 = nb0;
      if constexpr (BN == 128) w1 = nb1;
    } else {
#pragma unroll
      for (int j = 0; j < 4; j++) { w0[j] = (__bf16)g0[j]; w0[j + 4] = (__bf16)g1[j]; }
      if constexpr (BN == 128) {
#pragma unroll
        for (int j = 0; j < 4; j++) { w1[j] = (__bf16)g2[j]; w1[j + 4] = (__bf16)g3[j]; }
      }
    }
    *reinterpret_cast<bf16x8v*>(&lB[buf][lo]) = w0;
    if constexpr (BN == 128)
      *reinterpret_cast<bf16x8v*>(&lB[buf][lo + 2048]) = w1;
  };

  // prologue: tile 0 -> buf 0
  issue(0, 0);
  commitB(0);
  __syncthreads();                            // drains gload_lds + B visible

  int cur = 0;
  for (int k0 = 0; k0 < K; k0 += 32) {
    const bool nx = (k0 + 32 < K);
    if (nx) issue(k0 + 32, cur ^ 1);          // loads in flight across compute

    bf16x8v af[4], bw[NJ];
#pragma unroll
    for (int i = 0; i < 4; i++)
      af[i] = *reinterpret_cast<const bf16x8v*>(&lA[cur][(wr0 + i * 16 + fr) * 32 + q8]);
#pragma unroll
    for (int j = 0; j < NJ; j++)
      bw[j] = *reinterpret_cast<const bf16x8v*>(&lB[cur][(wc0 + j * 16 + fr) * 32 + q8]);
#pragma unroll
    for (int i = 0; i < 4; i++)
#pragma unroll
      for (int j = 0; j < NJ; j++)
        acc[i][j] = __builtin_amdgcn_mfma_f32_16x16x32_bf16(af[i], bw[j], acc[i][j], 0, 0, 0);

    if (nx) commitB(cur ^ 1);                 // vmcnt wait hidden under MFMAs
    __syncthreads();                          // single barrier per K-step
    cur ^= 1;
  }

  const int quad = (lane >> 4) * 4;
#pragma unroll
  for (int j = 0; j < NJ; j++) {
    const int col = col0 + wc0 + j * 16 + fr;
    const float bvf = (float)bias[col];
#pragma unroll
    for (int i = 0; i < 4; i++) {
      const int r0 = row0 + wr0 + i * 16 + quad;
#pragma unroll
      for (int r = 0; r < 4; r++) {
        float v = acc[i][j][r] + bvf;
        if (EPI == 1) v = fmaxf(v, 0.f);
        C[(size_t)(r0 + r) * N + col] = (bf16)v;
      }
    }
  }
}

template<int EPI, int BN>
__global__ __launch_bounds__(256) void gemm_nt(
    const bf16* __restrict__ A, const void* __restrict__ Wp, size_t woff,
    const bf16* __restrict__ bias, bf16* __restrict__ C,
    int M, int N, int K, const int* __restrict__ dflag)
{
  gemm_core<EPI, BN>(A, Wp, woff, bias, C, N, K, *dflag,
                     blockIdx.x * 128, blockIdx.y * BN);
}

// Fused Q/K/V projection: one N=3072 launch (768 blocks = 3/CU vs 3x256=1/CU).
// Each 128-col block lies entirely inside one of the three 1024-col tensors
// (128 | 1024), so W / bias / C are selected per-block (uniform branch).
__global__ __launch_bounds__(256) void gemm_qkv(
    const bf16* __restrict__ A,
    const void* __restrict__ Wq, const void* __restrict__ Wk, const void* __restrict__ Wv,
    size_t woff,
    const bf16* __restrict__ bq, const bf16* __restrict__ bk, const bf16* __restrict__ bv,
    bf16* __restrict__ Cq, bf16* __restrict__ Ck, bf16* __restrict__ Cv,
    int K, const int* __restrict__ dflag)
{
  const int cg = blockIdx.y * 128;
  const int t  = cg >> 10;
  const void* W    = (t == 0) ? Wq : (t == 1) ? Wk : Wv;
  const bf16* bias = (t == 0) ? bq : (t == 1) ? bk : bv;
  bf16*       C    = (t == 0) ? Cq : (t == 1) ? Ck : Cv;
  gemm_core<0, 128>(A, W, woff, bias, C, 1024, K, *dflag,
                    blockIdx.x * 128, cg & 1023);
}

// ---------------------------------------------------------------------------
// Band-sparse attention, MFMA version. One block = 32 query rows of one
// (b,h); band span <= 124, padded to 128 keys (K/V zero-filled past L).
// MASKING: both |s-t|<=WBAND AND c<L are required. The c<L check is NOT
// redundant at the tail blocks: when thi clamps to SEQL-1, phantom columns
// c>=L have t=tlo+c numerically within the band of late rows (e.g. s=2047,
// t=2048) and their zero-filled K gives score 0, which would otherwise
// inflate the softmax denominator (round-1 failure, absmax 0.54).
//
// QK^T: M=32(q) N=128(key) K=64(d), 16 tiles of 16x16x32 (2 k-steps), 4 per
// wave. PV: M=32(q) N=64(d) K=128(key), needs B[n=d][k=key] = V^T, so V is
// staged transposed. All LDS tiles XOR-swizzled (elem ^= (row&7)<<3; f32
// score tile (row&7)<<2) so ds_read_b128 fragment reads sit at the 2-way /
// bandwidth floor (G4: row-major [*][64/128] tiles are otherwise 16-32-way).
// O may alias Q: the block's Q reads are staged to LDS before any O write,
// and blocks touch disjoint (rows x head-cols) slices.
// ---------------------------------------------------------------------------
#define SKI(t, d)  ((((t) * 64) + (d)) ^ (((t) & 7) << 3))   // sQf / sKf (64-wide)
#define SVI(d, t)  ((((d) * 128) + (t)) ^ (((d) & 7) << 3))  // sVtf (128-wide)
#define SPI(q, c)  ((((q) * 128) + (c)) ^ (((q) & 7) << 3))  // sPf
#define SSI(q, c)  ((((q) * 128) + (c)) ^ (((q) & 7) << 2))  // sSf (f32)

__global__ __launch_bounds__(256) void attn_band(
    const bf16* __restrict__ Q, const bf16* __restrict__ Kp,
    const bf16* __restrict__ Vp, bf16* __restrict__ O)
{
  const int sblk = blockIdx.x;
  const int bh   = blockIdx.y;
  const int b    = bh >> 4;
  const int h    = bh & 15;
  const int s0   = sblk * 32;
  int tlo = s0 - WBAND;       if (tlo < 0) tlo = 0;
  int thi = s0 + 31 + WBAND;  if (thi > SEQL - 1) thi = SEQL - 1;
  const int L = thi - tlo + 1;           // 78..124

  __shared__ __align__(16) bf16  sQf[32 * 64];
  __shared__ __align__(16) bf16  sKf[128 * 64];
  __shared__ __align__(16) bf16  sVtf[64 * 128];
  __shared__ __align__(16) float sSf[32 * 128];
  __shared__ __align__(16) bf16  sPf[32 * 128];
  __shared__ float red1[32][8];
  __shared__ float red2[32][8];
  __shared__ float sInv[32];

  const int tid  = threadIdx.x;
  const int wave = tid >> 6;
  const int lane = tid & 63;
  const size_t base = ((size_t)b * SEQL) * EMBED + (size_t)h * HD;

  bf16x8v vz;
#pragma unroll
  for (int j = 0; j < 8; j++) vz[j] = (__bf16)0.f;

  // --- stage Q (32x64): one bf16x8 per thread
  {
    const int sl = tid >> 3, d0 = (tid & 7) * 8;
    *reinterpret_cast<bf16x8v*>(&sQf[SKI(sl, d0)]) =
        *reinterpret_cast<const bf16x8v*>(&Q[base + (size_t)(s0 + sl) * EMBED + d0]);
  }
  // --- stage K (128x64), zero-padded rows >= L
  for (int i = tid; i < 128 * 8; i += 256) {
    const int tl = i >> 3, d0 = (i & 7) * 8;
    bf16x8v v = vz;
    if (tl < L)
      v = *reinterpret_cast<const bf16x8v*>(&Kp[base + (size_t)(tlo + tl) * EMBED + d0]);
    *reinterpret_cast<bf16x8v*>(&sKf[SKI(tl, d0)]) = v;
  }
  // --- stage V transposed (d-major rows): lane-consecutive tl keeps the
  // scalar LDS column-writes 2-way (conflict floor); global is 16B/lane.
  for (int i = tid; i < 128 * 8; i += 256) {
    const int tl = i & 127, d0 = ((i >> 7) & 7) * 8;
    bf16x8v v = vz;
    if (tl < L)
      v = *reinterpret_cast<const bf16x8v*>(&Vp[base + (size_t)(tlo + tl) * EMBED + d0]);
#pragma unroll
    for (int j = 0; j < 8; j++)
      sVtf[SVI(d0 + j, tl)] = reinterpret_cast<const bf16*>(&v)[j];
  }
  __syncthreads();

  const int fr   = lane & 15;
  const int q8   = (lane >> 4) * 8;
  const int quad = (lane >> 4) * 4;

  // --- QK^T: wave w owns n-tiles {2w, 2w+1} x m-tiles {0,1}
  {
    f32x4v acc[2][2];
#pragma unroll
    for (int mi = 0; mi < 2; mi++)
#pragma unroll
      for (int nj = 0; nj < 2; nj++) acc[mi][nj] = (f32x4v){0.f, 0.f, 0.f, 0.f};
#pragma unroll
    for (int ks = 0; ks < 2; ks++) {
      bf16x8v a0 = *reinterpret_cast<const bf16x8v*>(&sQf[SKI(fr,      ks * 32 + q8)]);
      bf16x8v a1 = *reinterpret_cast<const bf16x8v*>(&sQf[SKI(16 + fr, ks * 32 + q8)]);
      bf16x8v b0 = *reinterpret_cast<const bf16x8v*>(&sKf[SKI((wave * 2    ) * 16 + fr, ks * 32 + q8)]);
      bf16x8v b1 = *reinterpret_cast<const bf16x8v*>(&sKf[SKI((wave * 2 + 1) * 16 + fr, ks * 32 + q8)]);
      acc[0][0] = __builtin_amdgcn_mfma_f32_16x16x32_bf16(a0, b0, acc[0][0], 0, 0, 0);
      acc[0][1] = __builtin_amdgcn_mfma_f32_16x16x32_bf16(a0, b1, acc[0][1], 0, 0, 0);
      acc[1][0] = __builtin_amdgcn_mfma_f32_16x16x32_bf16(a1, b0, acc[1][0], 0, 0, 0);
      acc[1][1] = __builtin_amdgcn_mfma_f32_16x16x32_bf16(a1, b1, acc[1][1], 0, 0, 0);
    }
    // mask + scale + store scores; needs BOTH the band check and c < L
    // (phantom tail columns pass the band check at clamped-thi blocks)
#pragma unroll
    for (int nj = 0; nj < 2; nj++) {
      const int c = (wave * 2 + nj) * 16 + fr;
      const int t = tlo + c;
      const bool cvalid = (c < L);
#pragma unroll
      for (int mi = 0; mi < 2; mi++) {
#pragma unroll
        for (int r = 0; r < 4; r++) {
          const int row = mi * 16 + quad + r;
          int dd = (s0 + row) - t; if (dd < 0) dd = -dd;
          sSf[SSI(row, c)] = (cvalid && dd <= WBAND) ? acc[mi][nj][r] * 0.125f
                                                     : -1e30f;
        }
      }
    }
  }
  __syncthreads();

  // --- softmax over 128 cols, 8 partitions per row (row = tid&31)
  const int sl   = tid & 31;
  const int part = tid >> 5;
  float pmax = -1e30f;
#pragma unroll
  for (int k = 0; k < 16; k++) pmax = fmaxf(pmax, sSf[SSI(sl, part + 8 * k)]);
  red1[sl][part] = pmax;
  __syncthreads();
  float rmax = red1[sl][0];
#pragma unroll
  for (int p = 1; p < 8; p++) rmax = fmaxf(rmax, red1[sl][p]);

  float psum = 0.f;
#pragma unroll
  for (int k = 0; k < 16; k++) {
    const int c = part + 8 * k;
    float e = __expf(sSf[SSI(sl, c)] - rmax);   // masked/padded -> exactly 0
    sPf[SPI(sl, c)] = (bf16)e;
    psum += e;
  }
  red2[sl][part] = psum;
  __syncthreads();
  float rsum = 0.f;
#pragma unroll
  for (int p = 0; p < 8; p++) rsum += red2[sl][p];
  if (part == 0) sInv[sl] = 1.f / rsum;
  __syncthreads();                              // sPf + sInv ready

  // --- PV: O[32,64] = P[32,128] @ V. wave w: m-tile w>>1, n-tiles (w&1)*2+{0,1}
  {
    const int mi = wave >> 1;
    const int nb = (wave & 1) * 2;
    f32x4v acc[2];
    acc[0] = (f32x4v){0.f, 0.f, 0.f, 0.f};
    acc[1] = (f32x4v){0.f, 0.f, 0.f, 0.f};
#pragma unroll
    for (int ks = 0; ks < 4; ks++) {
      bf16x8v a  = *reinterpret_cast<const bf16x8v*>(&sPf[SPI(mi * 16 + fr, ks * 32 + q8)]);
      bf16x8v b0 = *reinterpret_cast<const bf16x8v*>(&sVtf[SVI((nb    ) * 16 + fr, ks * 32 + q8)]);
      bf16x8v b1 = *reinterpret_cast<const bf16x8v*>(&sVtf[SVI((nb + 1) * 16 + fr, ks * 32 + q8)]);
      acc[0] = __builtin_amdgcn_mfma_f32_16x16x32_bf16(a, b0, acc[0], 0, 0, 0);
      acc[1] = __builtin_amdgcn_mfma_f32_16x16x32_bf16(a, b1, acc[1], 0, 0, 0);
    }
#pragma unroll
    for (int nj = 0; nj < 2; nj++) {
      const int d = (nb + nj) * 16 + fr;
#pragma unroll
      for (int r = 0; r < 4; r++) {
        const int row = mi * 16 + quad + r;
        O[base + (size_t)(s0 + row) * EMBED + d] = (bf16)(acc[nj][r] * sInv[row]);
      }
    }
  }
}

// ---------------------------------------------------------------------------
// Fused residual add + LayerNorm. fp32 residual in/out (xin may == xf_out),
// bf16 GEMM-branch input y, bf16 activation out. Optional final output:
// dtype keyed off dflag (fp32 world -> float*, bf16 world -> bf16*).
// ---------------------------------------------------------------------------
__global__ __launch_bounds__(256) void resid_ln(
    const float* xin, const bf16* __restrict__ y,
    const bf16* __restrict__ g, const bf16* __restrict__ be,
    float* xf_out, bf16* __restrict__ xb_out,
    void* __restrict__ final_out, const int* __restrict__ dflag)
{
  __shared__ float red1[4];
  __shared__ float red2[4];
  const int row = blockIdx.x;
  const int tid = threadIdx.x;
  const size_t base = (size_t)row * EMBED + (size_t)tid * 4;

  f32x4v  xv = *reinterpret_cast<const f32x4v*>(xin + base);
  bf16x4v yv = *reinterpret_cast<const bf16x4v*>(y + base);
  float v[4];
#pragma unroll
  for (int j = 0; j < 4; j++) v[j] = xv[j] + (float)yv[j];

  float s = v[0] + v[1] + v[2] + v[3];
#pragma unroll
  for (int off = 32; off > 0; off >>= 1) s += __shfl_down(s, off, 64);
  if ((tid & 63) == 0) red1[tid >> 6] = s;
  __syncthreads();
  const float mu = (red1[0] + red1[1] + red1[2] + red1[3]) * (1.f / EMBED);

  float sq = 0.f;
#pragma unroll
  for (int j = 0; j < 4; j++) { const float d = v[j] - mu; sq += d * d; }
#pragma unroll
  for (int off = 32; off > 0; off >>= 1) sq += __shfl_down(sq, off, 64);
  if ((tid & 63) == 0) red2[tid >> 6] = sq;
  __syncthreads();
  const float rstd = rsqrtf((red2[0] + red2[1] + red2[2] + red2[3]) * (1.f / EMBED) + LN_EPS);

  bf16x4v gv = *reinterpret_cast<const bf16x4v*>(g + (size_t)tid * 4);
  bf16x4v bv = *reinterpret_cast<const bf16x4v*>(be + (size_t)tid * 4);
  f32x4v of;
  bf16x4v ov;
#pragma unroll
  for (int j = 0; j < 4; j++) {
    of[j] = (v[j] - mu) * rstd * (float)gv[j] + (float)bv[j];
    ov[j] = (__bf16)of[j];
  }
  *reinterpret_cast<f32x4v*>(xf_out + base) = of;
  *reinterpret_cast<bf16x4v*>(xb_out + base) = ov;
  if (final_out) {
    if (*dflag)
      *reinterpret_cast<bf16x4v*>((bf16*)final_out + base) = ov;
    else
      *reinterpret_cast<f32x4v*>((float*)final_out + base) = of;
  }
}

// ---------------------------------------------------------------------------
// ws layout (65 MB peak, liveness-verified):
//  [0,4K) flag | [4K,~112K) bf16 param copies
//  [ 1,17) xf fp32 residual | [17,25) xb bf16 activation
//  [25,33) q (=ao alias)    | [33,41) kk | [41,49) vv
//  [25,57) hh 32MB (aliases q/kk/vv + free [49,57); all dead at FF1)
//  [57,65) y bf16 GEMM out  (disjoint from hh: FF2 reads hh, writes y)
// ---------------------------------------------------------------------------
extern "C" void kernel_launch(void* const* d_in, const int* in_sizes, int n_in,
                              void* d_out, int out_size, void* d_ws, size_t ws_size,
                              hipStream_t stream)
{
  char* ws = (char*)d_ws;
  const size_t MB = 1024 * 1024;
  int*   flag = (int*)ws;
  bf16*  pp   = (bf16*)(ws + 4096);
  float* xf   = (float*)(ws + 1 * MB);
  bf16*  xb   = (bf16*)(ws + 17 * MB);
  bf16*  q    = (bf16*)(ws + 25 * MB);
  bf16*  kk   = (bf16*)(ws + 33 * MB);
  bf16*  vv   = (bf16*)(ws + 41 * MB);
  bf16*  ao   = q;
  bf16*  hh   = (bf16*)(ws + 25 * MB);     // 32 MB
  bf16*  y    = (bf16*)(ws + 57 * MB);

  // bf16 param-copy element offsets within pp
  bf16* pbq = pp;            bf16* pbk = pp + 4096;  bf16* pbv = pp + 8192;
  bf16* pbo = pp + 12288;    bf16* pb1 = pp + 16384; bf16* pb2 = pp + 32768;
  bf16* pg1 = pp + 36864;    bf16* pe1 = pp + 40960;
  bf16* pg2 = pp + 45056;    bf16* pe2 = pp + 49152;

  detect_dtype<<<1, 256, 0, stream>>>((const unsigned int*)d_in[0], flag);

  cast_param<<<16, 256, 0, stream>>>(d_in[2],  pbq, 4096,  flag);
  cast_param<<<16, 256, 0, stream>>>(d_in[4],  pbk, 4096,  flag);
  cast_param<<<16, 256, 0, stream>>>(d_in[6],  pbv, 4096,  flag);
  cast_param<<<16, 256, 0, stream>>>(d_in[8],  pbo, 4096,  flag);
  cast_param<<<64, 256, 0, stream>>>(d_in[10], pb1, 16384, flag);
  cast_param<<<16, 256, 0, stream>>>(d_in[12], pb2, 4096,  flag);
  cast_param<<<16, 256, 0, stream>>>(d_in[13], pg1, 4096,  flag);
  cast_param<<<16, 256, 0, stream>>>(d_in[14], pe1, 4096,  flag);
  cast_param<<<16, 256, 0, stream>>>(d_in[15], pg2, 4096,  flag);
  cast_param<<<16, 256, 0, stream>>>(d_in[16], pe2, 4096,  flag);

  cast_in<<<dim3((NTOK * EMBED) / 256), 256, 0, stream>>>(
      d_in[0], xf, xb, NTOK * EMBED, flag);

  for (int l = 0; l < 4; l++) {
    const size_t wEE = (size_t)l * EMBED * EMBED;
    const size_t wFE = (size_t)l * FF_DIM * EMBED;

    gemm_qkv<<<dim3(32, 24), 256, 0, stream>>>(
        xb, d_in[1], d_in[3], d_in[5], wEE,
        pbq + l * 1024, pbk + l * 1024, pbv + l * 1024,
        q, kk, vv, EMBED, flag);
    attn_band<<<dim3(SEQL / 32, 32), 256, 0, stream>>>(q, kk, vv, ao);
    gemm_nt<0, 64><<<dim3(32, 16), 256, 0, stream>>>(
        ao, d_in[7], wEE, pbo + l * 1024, y, NTOK, EMBED, EMBED, flag);
    resid_ln<<<dim3(NTOK), 256, 0, stream>>>(xf, y, pg1 + l * 1024, pe1 + l * 1024, xf, xb, nullptr, flag);
    gemm_nt<1, 128><<<dim3(32, 32), 256, 0, stream>>>(
        xb, d_in[9], wFE, pb1 + l * 4096, hh, NTOK, FF_DIM, EMBED, flag);
    gemm_nt<0, 64><<<dim3(32, 16), 256, 0, stream>>>(
        hh, d_in[11], wFE, pb2 + l * 1024, y, NTOK, EMBED, FF_DIM, flag);
    resid_ln<<<dim3(NTOK), 256, 0, stream>>>(xf, y, pg2 + l * 1024, pe2 + l * 1024, xf, xb,
                                             l == 3 ? d_out : nullptr, flag);
  }
}

// Round 5
// 1200.838 us; speedup vs baseline: 1.4322x; 1.4322x over previous
//
#include <hip/hip_runtime.h>
#include <hip/hip_bf16.h>

using bf16 = __hip_bfloat16;
typedef __bf16 bf16x8v __attribute__((ext_vector_type(8)));
typedef __bf16 bf16x4v __attribute__((ext_vector_type(4)));
typedef float f32x4v __attribute__((ext_vector_type(4)));

#define EMBED 1024
#define FF_DIM 4096
#define NTOK 4096          // BATCH * SEQ
#define SEQL 2048
#define HD 64
#define WBAND 46           // ceil(sqrt(2048))
#define LN_EPS 1e-5f

// async global->LDS, 16B per lane. LDS dest must be wave-uniform base +
// lane*16B (m104/m108); all staging layouts here use lds_off = tid*8 bf16
// elems = wave-uniform + lane*16B. Addresses are STATIC (single buffer) --
// round-4's runtime-indexed double buffer defeated the scheduler (SGPR 32->
// 112, MfmaUtil 11.5->9, +28% time): compiler couldn't disambiguate the
// async LDS writes from ds_reads of the other buffer.
__device__ __forceinline__ void gload16(const bf16* g, bf16* l)
{
  __builtin_amdgcn_global_load_lds(
      (const __attribute__((address_space(1))) void*)g,
      (__attribute__((address_space(3))) void*)l, 16, 0, 0);
}

// ---------------------------------------------------------------------------
// Input-dtype detection (robust): fp32 tensors have random mantissa bits in
// the low halfword (sane-bf16-exponent rate ~20%); bf16 tensors have a real
// N(0,1) bf16 there (rate ~100%). flag: 1 = bf16 inputs, 0 = fp32 inputs.
// ---------------------------------------------------------------------------
__global__ __launch_bounds__(256) void detect_dtype(
    const unsigned int* __restrict__ xw, int* __restrict__ flag)
{
  __shared__ int votes[256];
  int v = 0;
#pragma unroll
  for (int j = 0; j < 4; j++) {
    unsigned int w = xw[1 + threadIdx.x * 4 + j];
    unsigned int e = (w >> 7) & 0xFFu;          // low halfword's bf16 exponent
    v += (e == 0u || (e >= 0x58u && e <= 0x88u)) ? 1 : 0;
  }
  votes[threadIdx.x] = v;
  __syncthreads();
  if (threadIdx.x == 0) {
    int s = 0;
    for (int i = 0; i < 256; i++) s += votes[i];
    *flag = (s > 512) ? 1 : 0;
  }
}

// generic param cast -> bf16 internal copy (biases / LN gains), flag-branched
__global__ __launch_bounds__(256) void cast_param(
    const void* __restrict__ src, bf16* __restrict__ dst, int n,
    const int* __restrict__ dflag)
{
  const int is_bf16 = *dflag;
  for (int i = blockIdx.x * 256 + threadIdx.x; i < n; i += gridDim.x * 256)
    dst[i] = is_bf16 ? ((const bf16*)src)[i] : (bf16)(((const float*)src)[i]);
}

// x -> fp32 residual stream + bf16 activation copy, flag-branched
__global__ __launch_bounds__(256) void cast_in(
    const void* __restrict__ x, float* __restrict__ xf,
    bf16* __restrict__ xb, int n, const int* __restrict__ dflag)
{
  const int is_bf16 = *dflag;
  const int i = blockIdx.x * 256 + threadIdx.x;
  if (i < n) {
    float v = is_bf16 ? (float)((const bf16*)x)[i] : ((const float*)x)[i];
    xf[i] = v;
    xb[i] = (bf16)v;
  }
}

// ---------------------------------------------------------------------------
// Per-layer weight conversion -> contiguous bf16 scratch (24 MB):
//  [0,1M)   Wq[l]   [1M,2M) Wk[l]   [2M,3M) Wv[l]   [3M,4M) Wo[l]
//  [4M,8M)  W1[l]   [8M,12M) W2[l]          (elem offsets, 12.58M elems)
// Wq/Wk/Wv stacked = one [3072,1024] matrix for the fused QKV GEMM.
// One-time per layer (~36 MB read + 24 MB write ~= 10 us); lets every GEMM
// use pure-bf16 global_load_lds for BOTH operands (m97 structure) and halves
// weight fetch bytes in the fp32-input world.
// ---------------------------------------------------------------------------
__global__ __launch_bounds__(256) void cast_weights(
    const void* __restrict__ wq, const void* __restrict__ wk,
    const void* __restrict__ wv, const void* __restrict__ wo,
    const void* __restrict__ w1, const void* __restrict__ w2,
    size_t off_ee, size_t off_fe, bf16* __restrict__ dst,
    const int* __restrict__ dflag)
{
  const int is_bf16 = *dflag;
  const int c = blockIdx.x * 256 + threadIdx.x;     // 1,572,864 chunks of 8
  const size_t i = (size_t)c * 8;
  const void* src;
  size_t si;
  if (i < 4194304) {                                // four EMBEDxEMBED tensors
    const int t = (int)(i >> 20);
    src = (t == 0) ? wq : (t == 1) ? wk : (t == 2) ? wv : wo;
    si  = off_ee + (i & 1048575);
  } else if (i < 8388608) { src = w1; si = off_fe + (i - 4194304); }
  else                    { src = w2; si = off_fe + (i - 8388608); }
  bf16x8v o;
  if (is_bf16) {
    o = *reinterpret_cast<const bf16x8v*>((const bf16*)src + si);
  } else {
    f32x4v a = *reinterpret_cast<const f32x4v*>((const float*)src + si);
    f32x4v b = *reinterpret_cast<const f32x4v*>((const float*)src + si + 4);
#pragma unroll
    for (int j = 0; j < 4; j++) { o[j] = (__bf16)a[j]; o[j + 4] = (__bf16)b[j]; }
  }
  *reinterpret_cast<bf16x8v*>(dst + i) = o;
}

// ---------------------------------------------------------------------------
// NT GEMM core (m97-exact): C[128 x BN] = A[M,K] @ W[N,K]^T + bias[N].
// Both operands bf16; staged via global_load_lds width=16 into a SINGLE
// static LDS buffer; 2 barriers per BK=32 step:
//   barrier (WAR: prev readers done) | issue 3-4 gload_lds | barrier (vmcnt
//   drain, staging visible) | ds_read_b128 frags | 8/16 MFMA.
// Latency at the drain is hidden by co-resident blocks (2-4/CU).
// Verified MFMA layouts (m89/m91): A/B-frag row=lane&15,k=(lane>>4)*8+j;
// C/D col=lane&15, row=(lane>>4)*4+reg.  EPI: 1 = relu.
// col0W: column offset into W's rows (differs from col0C only for fused QKV).
// ---------------------------------------------------------------------------
template<int EPI, int BN>
__device__ __forceinline__ void gemm_core(
    const bf16* __restrict__ A, const bf16* __restrict__ W,
    const bf16* __restrict__ bias, bf16* __restrict__ C,
    int N, int K, int row0, int col0W, int col0C)
{
  __shared__ __align__(16) bf16 lA[128 * 32];
  __shared__ __align__(16) bf16 lB[BN * 32];
  constexpr int NJ = BN / 32;

  const int tid  = threadIdx.x;
  const int wave = tid >> 6;
  const int lane = tid & 63;
  const int wr0  = (wave >> 1) * 64;
  const int wc0  = (wave & 1) * (BN / 2);

  f32x4v acc[4][NJ];
#pragma unroll
  for (int i = 0; i < 4; i++)
#pragma unroll
    for (int j = 0; j < NJ; j++) acc[i][j] = (f32x4v){0.f, 0.f, 0.f, 0.f};

  // A staging: row = wave*16 + lane/4 (+64 second 16B), kchunk=(lane&3)*8;
  // lds elem off = tid*8 (linear, wave-uniform base + lane*16B).
  const int srow = wave * 16 + (lane >> 2);
  const int skc  = (lane & 3) * 8;
  const bf16* Ag = A + (size_t)(row0 + srow) * K + skc;
  const bf16* Bg;
  if constexpr (BN == 128) Bg = W + (size_t)(col0W + srow) * K + skc;
  else                     Bg = W + (size_t)(col0W + (tid >> 2)) * K + (size_t)(tid & 3) * 8;
  bf16* lAp = lA + tid * 8;
  bf16* lBp = lB + tid * 8;

  const int fr = lane & 15;
  const int q8 = (lane >> 4) * 8;

  for (int k0 = 0; k0 < K; k0 += 32) {
    __syncthreads();                          // WAR: previous iter's readers done
    gload16(Ag + k0, lAp);
    gload16(Ag + (size_t)64 * K + k0, lAp + 2048);
    gload16(Bg + k0, lBp);
    if constexpr (BN == 128)
      gload16(Bg + (size_t)64 * K + k0, lBp + 2048);
    __syncthreads();                          // vmcnt drain: staging visible

    bf16x8v af[4], bw[NJ];
#pragma unroll
    for (int i = 0; i < 4; i++)
      af[i] = *reinterpret_cast<const bf16x8v*>(&lA[(wr0 + i * 16 + fr) * 32 + q8]);
#pragma unroll
    for (int j = 0; j < NJ; j++)
      bw[j] = *reinterpret_cast<const bf16x8v*>(&lB[(wc0 + j * 16 + fr) * 32 + q8]);
#pragma unroll
    for (int i = 0; i < 4; i++)
#pragma unroll
      for (int j = 0; j < NJ; j++)
        acc[i][j] = __builtin_amdgcn_mfma_f32_16x16x32_bf16(af[i], bw[j], acc[i][j], 0, 0, 0);
  }

  const int quad = (lane >> 4) * 4;
#pragma unroll
  for (int j = 0; j < NJ; j++) {
    const int col = col0C + wc0 + j * 16 + fr;
    const float bvf = (float)bias[col];
#pragma unroll
    for (int i = 0; i < 4; i++) {
      const int r0 = row0 + wr0 + i * 16 + quad;
#pragma unroll
      for (int r = 0; r < 4; r++) {
        float v = acc[i][j][r] + bvf;
        if (EPI == 1) v = fmaxf(v, 0.f);
        C[(size_t)(r0 + r) * N + col] = (bf16)v;
      }
    }
  }
}

template<int EPI, int BN>
__global__ __launch_bounds__(256) void gemm_bt(
    const bf16* __restrict__ A, const bf16* __restrict__ W,
    const bf16* __restrict__ bias, bf16* __restrict__ C, int N, int K)
{
  gemm_core<EPI, BN>(A, W, bias, C, N, K,
                     blockIdx.x * 128, blockIdx.y * BN, blockIdx.y * BN);
}

// Fused Q/K/V projection: Wqkv is the contiguous [3072,1024] bf16 stack; one
// 768-block launch (3 blocks/CU vs 3x256=1/CU). Each 128-col block lies in
// one output tensor (128 | 1024) -> bias/C selected per block (uniform).
__global__ __launch_bounds__(256) void gemm_qkv(
    const bf16* __restrict__ A, const bf16* __restrict__ Wqkv,
    const bf16* __restrict__ bq, const bf16* __restrict__ bk, const bf16* __restrict__ bv,
    bf16* __restrict__ Cq, bf16* __restrict__ Ck, bf16* __restrict__ Cv, int K)
{
  const int cg = blockIdx.y * 128;             // 0..2944, global W row
  const int t  = cg >> 10;
  const bf16* bias = (t == 0) ? bq : (t == 1) ? bk : bv;
  bf16*       C    = (t == 0) ? Cq : (t == 1) ? Ck : Cv;
  gemm_core<0, 128>(A, Wqkv, bias, C, 1024, K,
                    blockIdx.x * 128, cg, cg & 1023);
}

// ---------------------------------------------------------------------------
// Band-sparse attention, MFMA version. One block = 32 query rows of one
// (b,h); band span <= 124, padded to 128 keys (K/V zero-filled past L).
// MASKING: both |s-t|<=WBAND AND c<L are required. The c<L check is NOT
// redundant at the tail blocks: when thi clamps to SEQL-1, phantom columns
// c>=L have t=tlo+c numerically within the band of late rows (e.g. s=2047,
// t=2048) and their zero-filled K gives score 0, which would otherwise
// inflate the softmax denominator (round-1 failure, absmax 0.54).
//
// QK^T: M=32(q) N=128(key) K=64(d), 16 tiles of 16x16x32 (2 k-steps), 4 per
// wave. PV: M=32(q) N=64(d) K=128(key), needs B[n=d][k=key] = V^T, so V is
// staged transposed. All LDS tiles XOR-swizzled (elem ^= (row&7)<<3; f32
// score tile (row&7)<<2) so ds_read_b128 fragment reads sit at the 2-way /
// bandwidth floor (G4: row-major [*][64/128] tiles are otherwise 16-32-way).
// O may alias Q: the block's Q reads are staged to LDS before any O write,
// and blocks touch disjoint (rows x head-cols) slices.
// ---------------------------------------------------------------------------
#define SKI(t, d)  ((((t) * 64) + (d)) ^ (((t) & 7) << 3))   // sQf / sKf (64-wide)
#define SVI(d, t)  ((((d) * 128) + (t)) ^ (((d) & 7) << 3))  // sVtf (128-wide)
#define SPI(q, c)  ((((q) * 128) + (c)) ^ (((q) & 7) << 3))  // sPf
#define SSI(q, c)  ((((q) * 128) + (c)) ^ (((q) & 7) << 2))  // sSf (f32)

__global__ __launch_bounds__(256) void attn_band(
    const bf16* __restrict__ Q, const bf16* __restrict__ Kp,
    const bf16* __restrict__ Vp, bf16* __restrict__ O)
{
  const int sblk = blockIdx.x;
  const int bh   = blockIdx.y;
  const int b    = bh >> 4;
  const int h    = bh & 15;
  const int s0   = sblk * 32;
  int tlo = s0 - WBAND;       if (tlo < 0) tlo = 0;
  int thi = s0 + 31 + WBAND;  if (thi > SEQL - 1) thi = SEQL - 1;
  const int L = thi - tlo + 1;           // 78..124

  __shared__ __align__(16) bf16  sQf[32 * 64];
  __shared__ __align__(16) bf16  sKf[128 * 64];
  __shared__ __align__(16) bf16  sVtf[64 * 128];
  __shared__ __align__(16) float sSf[32 * 128];
  __shared__ __align__(16) bf16  sPf[32 * 128];
  __shared__ float red1[32][8];
  __shared__ float red2[32][8];
  __shared__ float sInv[32];

  const int tid  = threadIdx.x;
  const int wave = tid >> 6;
  const int lane = tid & 63;
  const size_t base = ((size_t)b * SEQL) * EMBED + (size_t)h * HD;

  bf16x8v vz;
#pragma unroll
  for (int j = 0; j < 8; j++) vz[j] = (__bf16)0.f;

  // --- stage Q (32x64): one bf16x8 per thread
  {
    const int sl = tid >> 3, d0 = (tid & 7) * 8;
    *reinterpret_cast<bf16x8v*>(&sQf[SKI(sl, d0)]) =
        *reinterpret_cast<const bf16x8v*>(&Q[base + (size_t)(s0 + sl) * EMBED + d0]);
  }
  // --- stage K (128x64), zero-padded rows >= L
  for (int i = tid; i < 128 * 8; i += 256) {
    const int tl = i >> 3, d0 = (i & 7) * 8;
    bf16x8v v = vz;
    if (tl < L)
      v = *reinterpret_cast<const bf16x8v*>(&Kp[base + (size_t)(tlo + tl) * EMBED + d0]);
    *reinterpret_cast<bf16x8v*>(&sKf[SKI(tl, d0)]) = v;
  }
  // --- stage V transposed (d-major rows): lane-consecutive tl keeps the
  // scalar LDS column-writes 2-way (conflict floor); global is 16B/lane.
  for (int i = tid; i < 128 * 8; i += 256) {
    const int tl = i & 127, d0 = ((i >> 7) & 7) * 8;
    bf16x8v v = vz;
    if (tl < L)
      v = *reinterpret_cast<const bf16x8v*>(&Vp[base + (size_t)(tlo + tl) * EMBED + d0]);
#pragma unroll
    for (int j = 0; j < 8; j++)
      sVtf[SVI(d0 + j, tl)] = reinterpret_cast<const bf16*>(&v)[j];
  }
  __syncthreads();

  const int fr   = lane & 15;
  const int q8   = (lane >> 4) * 8;
  const int quad = (lane >> 4) * 4;

  // --- QK^T: wave w owns n-tiles {2w, 2w+1} x m-tiles {0,1}
  {
    f32x4v acc[2][2];
#pragma unroll
    for (int mi = 0; mi < 2; mi++)
#pragma unroll
      for (int nj = 0; nj < 2; nj++) acc[mi][nj] = (f32x4v){0.f, 0.f, 0.f, 0.f};
#pragma unroll
    for (int ks = 0; ks < 2; ks++) {
      bf16x8v a0 = *reinterpret_cast<const bf16x8v*>(&sQf[SKI(fr,      ks * 32 + q8)]);
      bf16x8v a1 = *reinterpret_cast<const bf16x8v*>(&sQf[SKI(16 + fr, ks * 32 + q8)]);
      bf16x8v b0 = *reinterpret_cast<const bf16x8v*>(&sKf[SKI((wave * 2    ) * 16 + fr, ks * 32 + q8)]);
      bf16x8v b1 = *reinterpret_cast<const bf16x8v*>(&sKf[SKI((wave * 2 + 1) * 16 + fr, ks * 32 + q8)]);
      acc[0][0] = __builtin_amdgcn_mfma_f32_16x16x32_bf16(a0, b0, acc[0][0], 0, 0, 0);
      acc[0][1] = __builtin_amdgcn_mfma_f32_16x16x32_bf16(a0, b1, acc[0][1], 0, 0, 0);
      acc[1][0] = __builtin_amdgcn_mfma_f32_16x16x32_bf16(a1, b0, acc[1][0], 0, 0, 0);
      acc[1][1] = __builtin_amdgcn_mfma_f32_16x16x32_bf16(a1, b1, acc[1][1], 0, 0, 0);
    }
    // mask + scale + store scores; needs BOTH the band check and c < L
    // (phantom tail columns pass the band check at clamped-thi blocks)
#pragma unroll
    for (int nj = 0; nj < 2; nj++) {
      const int c = (wave * 2 + nj) * 16 + fr;
      const int t = tlo + c;
      const bool cvalid = (c < L);
#pragma unroll
      for (int mi = 0; mi < 2; mi++) {
#pragma unroll
        for (int r = 0; r < 4; r++) {
          const int row = mi * 16 + quad + r;
          int dd = (s0 + row) - t; if (dd < 0) dd = -dd;
          sSf[SSI(row, c)] = (cvalid && dd <= WBAND) ? acc[mi][nj][r] * 0.125f
                                                     : -1e30f;
        }
      }
    }
  }
  __syncthreads();

  // --- softmax over 128 cols, 8 partitions per row (row = tid&31)
  const int sl   = tid & 31;
  const int part = tid >> 5;
  float pmax = -1e30f;
#pragma unroll
  for (int k = 0; k < 16; k++) pmax = fmaxf(pmax, sSf[SSI(sl, part + 8 * k)]);
  red1[sl][part] = pmax;
  __syncthreads();
  float rmax = red1[sl][0];
#pragma unroll
  for (int p = 1; p < 8; p++) rmax = fmaxf(rmax, red1[sl][p]);

  float psum = 0.f;
#pragma unroll
  for (int k = 0; k < 16; k++) {
    const int c = part + 8 * k;
    float e = __expf(sSf[SSI(sl, c)] - rmax);   // masked/padded -> exactly 0
    sPf[SPI(sl, c)] = (bf16)e;
    psum += e;
  }
  red2[sl][part] = psum;
  __syncthreads();
  float rsum = 0.f;
#pragma unroll
  for (int p = 0; p < 8; p++) rsum += red2[sl][p];
  if (part == 0) sInv[sl] = 1.f / rsum;
  __syncthreads();                              // sPf + sInv ready

  // --- PV: O[32,64] = P[32,128] @ V. wave w: m-tile w>>1, n-tiles (w&1)*2+{0,1}
  {
    const int mi = wave >> 1;
    const int nb = (wave & 1) * 2;
    f32x4v acc[2];
    acc[0] = (f32x4v){0.f, 0.f, 0.f, 0.f};
    acc[1] = (f32x4v){0.f, 0.f, 0.f, 0.f};
#pragma unroll
    for (int ks = 0; ks < 4; ks++) {
      bf16x8v a  = *reinterpret_cast<const bf16x8v*>(&sPf[SPI(mi * 16 + fr, ks * 32 + q8)]);
      bf16x8v b0 = *reinterpret_cast<const bf16x8v*>(&sVtf[SVI((nb    ) * 16 + fr, ks * 32 + q8)]);
      bf16x8v b1 = *reinterpret_cast<const bf16x8v*>(&sVtf[SVI((nb + 1) * 16 + fr, ks * 32 + q8)]);
      acc[0] = __builtin_amdgcn_mfma_f32_16x16x32_bf16(a, b0, acc[0], 0, 0, 0);
      acc[1] = __builtin_amdgcn_mfma_f32_16x16x32_bf16(a, b1, acc[1], 0, 0, 0);
    }
#pragma unroll
    for (int nj = 0; nj < 2; nj++) {
      const int d = (nb + nj) * 16 + fr;
#pragma unroll
      for (int r = 0; r < 4; r++) {
        const int row = mi * 16 + quad + r;
        O[base + (size_t)(s0 + row) * EMBED + d] = (bf16)(acc[nj][r] * sInv[row]);
      }
    }
  }
}

// ---------------------------------------------------------------------------
// Fused residual add + LayerNorm. fp32 residual in/out (xin may == xf_out),
// bf16 GEMM-branch input y, bf16 activation out. Optional final output:
// dtype keyed off dflag (fp32 world -> float*, bf16 world -> bf16*).
// ---------------------------------------------------------------------------
__global__ __launch_bounds__(256) void resid_ln(
    const float* xin, const bf16* __restrict__ y,
    const bf16* __restrict__ g, const bf16* __restrict__ be,
    float* xf_out, bf16* __restrict__ xb_out,
    void* __restrict__ final_out, const int* __restrict__ dflag)
{
  __shared__ float red1[4];
  __shared__ float red2[4];
  const int row = blockIdx.x;
  const int tid = threadIdx.x;
  const size_t base = (size_t)row * EMBED + (size_t)tid * 4;

  f32x4v  xv = *reinterpret_cast<const f32x4v*>(xin + base);
  bf16x4v yv = *reinterpret_cast<const bf16x4v*>(y + base);
  float v[4];
#pragma unroll
  for (int j = 0; j < 4; j++) v[j] = xv[j] + (float)yv[j];

  float s = v[0] + v[1] + v[2] + v[3];
#pragma unroll
  for (int off = 32; off > 0; off >>= 1) s += __shfl_down(s, off, 64);
  if ((tid & 63) == 0) red1[tid >> 6] = s;
  __syncthreads();
  const float mu = (red1[0] + red1[1] + red1[2] + red1[3]) * (1.f / EMBED);

  float sq = 0.f;
#pragma unroll
  for (int j = 0; j < 4; j++) { const float d = v[j] - mu; sq += d * d; }
#pragma unroll
  for (int off = 32; off > 0; off >>= 1) sq += __shfl_down(sq, off, 64);
  if ((tid & 63) == 0) red2[tid >> 6] = sq;
  __syncthreads();
  const float rstd = rsqrtf((red2[0] + red2[1] + red2[2] + red2[3]) * (1.f / EMBED) + LN_EPS);

  bf16x4v gv = *reinterpret_cast<const bf16x4v*>(g + (size_t)tid * 4);
  bf16x4v bv = *reinterpret_cast<const bf16x4v*>(be + (size_t)tid * 4);
  f32x4v of;
  bf16x4v ov;
#pragma unroll
  for (int j = 0; j < 4; j++) {
    of[j] = (v[j] - mu) * rstd * (float)gv[j] + (float)bv[j];
    ov[j] = (__bf16)of[j];
  }
  *reinterpret_cast<f32x4v*>(xf_out + base) = of;
  *reinterpret_cast<bf16x4v*>(xb_out + base) = ov;
  if (final_out) {
    if (*dflag)
      *reinterpret_cast<bf16x4v*>((bf16*)final_out + base) = ov;
    else
      *reinterpret_cast<f32x4v*>((float*)final_out + base) = of;
  }
}

// ---------------------------------------------------------------------------
// ws layout (89 MB peak):
//  [0,4K) flag | [4K,~112K) bf16 param copies
//  [ 1,17) xf fp32 residual | [17,25) xb bf16 activation
//  [25,33) q (=ao alias)    | [33,41) kk | [41,49) vv
//  [25,57) hh 32MB (aliases q/kk/vv + free [49,57); all dead at FF1)
//  [57,65) y bf16 GEMM out  (disjoint from hh: FF2 reads hh, writes y)
//  [65,89) wbf: current layer's bf16 weights (Wqkv|Wo|W1|W2)
// ---------------------------------------------------------------------------
extern "C" void kernel_launch(void* const* d_in, const int* in_sizes, int n_in,
                              void* d_out, int out_size, void* d_ws, size_t ws_size,
                              hipStream_t stream)
{
  char* ws = (char*)d_ws;
  const size_t MB = 1024 * 1024;
  int*   flag = (int*)ws;
  bf16*  pp   = (bf16*)(ws + 4096);
  float* xf   = (float*)(ws + 1 * MB);
  bf16*  xb   = (bf16*)(ws + 17 * MB);
  bf16*  q    = (bf16*)(ws + 25 * MB);
  bf16*  kk   = (bf16*)(ws + 33 * MB);
  bf16*  vv   = (bf16*)(ws + 41 * MB);
  bf16*  ao   = q;
  bf16*  hh   = (bf16*)(ws + 25 * MB);     // 32 MB
  bf16*  y    = (bf16*)(ws + 57 * MB);
  bf16*  wbf  = (bf16*)(ws + 65 * MB);     // 24 MB bf16 weights (per layer)

  // bf16 param-copy element offsets within pp
  bf16* pbq = pp;            bf16* pbk = pp + 4096;  bf16* pbv = pp + 8192;
  bf16* pbo = pp + 12288;    bf16* pb1 = pp + 16384; bf16* pb2 = pp + 32768;
  bf16* pg1 = pp + 36864;    bf16* pe1 = pp + 40960;
  bf16* pg2 = pp + 45056;    bf16* pe2 = pp + 49152;

  detect_dtype<<<1, 256, 0, stream>>>((const unsigned int*)d_in[0], flag);

  cast_param<<<16, 256, 0, stream>>>(d_in[2],  pbq, 4096,  flag);
  cast_param<<<16, 256, 0, stream>>>(d_in[4],  pbk, 4096,  flag);
  cast_param<<<16, 256, 0, stream>>>(d_in[6],  pbv, 4096,  flag);
  cast_param<<<16, 256, 0, stream>>>(d_in[8],  pbo, 4096,  flag);
  cast_param<<<64, 256, 0, stream>>>(d_in[10], pb1, 16384, flag);
  cast_param<<<16, 256, 0, stream>>>(d_in[12], pb2, 4096,  flag);
  cast_param<<<16, 256, 0, stream>>>(d_in[13], pg1, 4096,  flag);
  cast_param<<<16, 256, 0, stream>>>(d_in[14], pe1, 4096,  flag);
  cast_param<<<16, 256, 0, stream>>>(d_in[15], pg2, 4096,  flag);
  cast_param<<<16, 256, 0, stream>>>(d_in[16], pe2, 4096,  flag);

  cast_in<<<dim3((NTOK * EMBED) / 256), 256, 0, stream>>>(
      d_in[0], xf, xb, NTOK * EMBED, flag);

  for (int l = 0; l < 4; l++) {
    // convert this layer's weights to bf16 (Wq|Wk|Wv stacked = fused QKV W)
    cast_weights<<<6144, 256, 0, stream>>>(
        d_in[1], d_in[3], d_in[5], d_in[7], d_in[9], d_in[11],
        (size_t)l * 1048576, (size_t)l * 4194304, wbf, flag);

    gemm_qkv<<<dim3(32, 24), 256, 0, stream>>>(
        xb, wbf, pbq + l * 1024, pbk + l * 1024, pbv + l * 1024,
        q, kk, vv, EMBED);
    attn_band<<<dim3(SEQL / 32, 32), 256, 0, stream>>>(q, kk, vv, ao);
    gemm_bt<0, 64><<<dim3(32, 16), 256, 0, stream>>>(
        ao, wbf + 3 * 1048576, pbo + l * 1024, y, EMBED, EMBED);
    resid_ln<<<dim3(NTOK), 256, 0, stream>>>(xf, y, pg1 + l * 1024, pe1 + l * 1024, xf, xb, nullptr, flag);
    gemm_bt<1, 128><<<dim3(32, 32), 256, 0, stream>>>(
        xb, wbf + 4 * 1048576, pb1 + l * 4096, hh, FF_DIM, EMBED);
    gemm_bt<0, 64><<<dim3(32, 16), 256, 0, stream>>>(
        hh, wbf + 8 * 1048576, pb2 + l * 1024, y, EMBED, FF_DIM);
    resid_ln<<<dim3(NTOK), 256, 0, stream>>>(xf, y, pg2 + l * 1024, pe2 + l * 1024, xf, xb,
                                             l == 3 ? d_out : nullptr, flag);
  }
}

// Round 6
// 1132.355 us; speedup vs baseline: 1.5189x; 1.0605x over previous
//
#include <hip/hip_runtime.h>
#include <hip/hip_bf16.h>

using bf16 = __hip_bfloat16;
typedef __bf16 bf16x8v __attribute__((ext_vector_type(8)));
typedef __bf16 bf16x4v __attribute__((ext_vector_type(4)));
typedef float f32x4v __attribute__((ext_vector_type(4)));

#define EMBED 1024
#define FF_DIM 4096
#define NTOK 4096          // BATCH * SEQ
#define SEQL 2048
#define HD 64
#define WBAND 46           // ceil(sqrt(2048))
#define LN_EPS 1e-5f

// async global->LDS, 16B per lane. LDS dest must be wave-uniform base +
// lane*16B (m104/m108); all staging layouts here use lds_off = tid*8 bf16
// elems = wave-uniform + lane*16B. Addresses are STATIC (single buffer) --
// round-4's runtime-indexed double buffer defeated the scheduler.
__device__ __forceinline__ void gload16(const bf16* g, bf16* l)
{
  __builtin_amdgcn_global_load_lds(
      (const __attribute__((address_space(1))) void*)g,
      (__attribute__((address_space(3))) void*)l, 16, 0, 0);
}

// ---------------------------------------------------------------------------
// Input-dtype detection: flag 1 = bf16 inputs, 0 = fp32 inputs.
// ---------------------------------------------------------------------------
__global__ __launch_bounds__(256) void detect_dtype(
    const unsigned int* __restrict__ xw, int* __restrict__ flag)
{
  __shared__ int votes[256];
  int v = 0;
#pragma unroll
  for (int j = 0; j < 4; j++) {
    unsigned int w = xw[1 + threadIdx.x * 4 + j];
    unsigned int e = (w >> 7) & 0xFFu;          // low halfword's bf16 exponent
    v += (e == 0u || (e >= 0x58u && e <= 0x88u)) ? 1 : 0;
  }
  votes[threadIdx.x] = v;
  __syncthreads();
  if (threadIdx.x == 0) {
    int s = 0;
    for (int i = 0; i < 256; i++) s += votes[i];
    *flag = (s > 512) ? 1 : 0;
  }
}

// generic param cast -> bf16 internal copy (biases / LN gains), flag-branched
__global__ __launch_bounds__(256) void cast_param(
    const void* __restrict__ src, bf16* __restrict__ dst, int n,
    const int* __restrict__ dflag)
{
  const int is_bf16 = *dflag;
  for (int i = blockIdx.x * 256 + threadIdx.x; i < n; i += gridDim.x * 256)
    dst[i] = is_bf16 ? ((const bf16*)src)[i] : (bf16)(((const float*)src)[i]);
}

// x -> fp32 residual stream + bf16 activation copy, flag-branched
__global__ __launch_bounds__(256) void cast_in(
    const void* __restrict__ x, float* __restrict__ xf,
    bf16* __restrict__ xb, int n, const int* __restrict__ dflag)
{
  const int is_bf16 = *dflag;
  const int i = blockIdx.x * 256 + threadIdx.x;
  if (i < n) {
    float v = is_bf16 ? (float)((const bf16*)x)[i] : ((const float*)x)[i];
    xf[i] = v;
    xb[i] = (bf16)v;
  }
}

// ---------------------------------------------------------------------------
// Per-layer weight conversion -> contiguous bf16 scratch (24 MB):
//  [0,1M) Wq  [1M,2M) Wk  [2M,3M) Wv  [3M,4M) Wo  [4M,8M) W1  [8M,12M) W2
// Wq/Wk/Wv stacked = one [3072,1024] matrix for the fused QKV GEMM.
// ---------------------------------------------------------------------------
__global__ __launch_bounds__(256) void cast_weights(
    const void* __restrict__ wq, const void* __restrict__ wk,
    const void* __restrict__ wv, const void* __restrict__ wo,
    const void* __restrict__ w1, const void* __restrict__ w2,
    size_t off_ee, size_t off_fe, bf16* __restrict__ dst,
    const int* __restrict__ dflag)
{
  const int is_bf16 = *dflag;
  const int c = blockIdx.x * 256 + threadIdx.x;     // 1,572,864 chunks of 8
  const size_t i = (size_t)c * 8;
  const void* src;
  size_t si;
  if (i < 4194304) {                                // four EMBEDxEMBED tensors
    const int t = (int)(i >> 20);
    src = (t == 0) ? wq : (t == 1) ? wk : (t == 2) ? wv : wo;
    si  = off_ee + (i & 1048575);
  } else if (i < 8388608) { src = w1; si = off_fe + (i - 4194304); }
  else                    { src = w2; si = off_fe + (i - 8388608); }
  bf16x8v o;
  if (is_bf16) {
    o = *reinterpret_cast<const bf16x8v*>((const bf16*)src + si);
  } else {
    f32x4v a = *reinterpret_cast<const f32x4v*>((const float*)src + si);
    f32x4v b = *reinterpret_cast<const f32x4v*>((const float*)src + si + 4);
#pragma unroll
    for (int j = 0; j < 4; j++) { o[j] = (__bf16)a[j]; o[j + 4] = (__bf16)b[j]; }
  }
  *reinterpret_cast<bf16x8v*>(dst + i) = o;
}

// ---------------------------------------------------------------------------
// NT GEMM core (m97-exact): C[128 x BN] = A[M,Kslice] @ W[N,Kslice]^T (+bias).
// Both operands bf16; staged via global_load_lds width=16 into a SINGLE
// static LDS buffer; 2 barriers per BK=32 step. Latency at the vmcnt drain
// is hidden by co-resident blocks -- round-6: split-K gives the N=1024 GEMMs
// 1024 blocks = 4/CU (was 2/CU, occupancy 20%, MfmaUtil 16%; FF1 at 4/CU is
// measurably faster at identical FLOPs).
// Kstride: row stride of A and W (full K). [Kbeg, Kbeg+Klen): this block's
// K-slice. bias == nullptr for non-first slices (partials sum in resid_ln).
// Verified MFMA layouts (m89/m91): A/B-frag row=lane&15,k=(lane>>4)*8+j;
// C/D col=lane&15, row=(lane>>4)*4+reg.  EPI: 1 = relu (only on NS=1 GEMMs).
// ---------------------------------------------------------------------------
template<int EPI, int BN>
__device__ __forceinline__ void gemm_core(
    const bf16* __restrict__ A, const bf16* __restrict__ W,
    const bf16* __restrict__ bias, bf16* __restrict__ C,
    int N, int Kstride, int Kbeg, int Klen,
    int row0, int col0W, int col0C)
{
  __shared__ __align__(16) bf16 lA[128 * 32];
  __shared__ __align__(16) bf16 lB[BN * 32];
  constexpr int NJ = BN / 32;

  const int tid  = threadIdx.x;
  const int wave = tid >> 6;
  const int lane = tid & 63;
  const int wr0  = (wave >> 1) * 64;
  const int wc0  = (wave & 1) * (BN / 2);

  f32x4v acc[4][NJ];
#pragma unroll
  for (int i = 0; i < 4; i++)
#pragma unroll
    for (int j = 0; j < NJ; j++) acc[i][j] = (f32x4v){0.f, 0.f, 0.f, 0.f};

  // A staging: row = wave*16 + lane/4 (+64 second 16B), kchunk=(lane&3)*8;
  // lds elem off = tid*8 (linear, wave-uniform base + lane*16B).
  const int srow = wave * 16 + (lane >> 2);
  const int skc  = (lane & 3) * 8;
  const bf16* Ag = A + (size_t)(row0 + srow) * Kstride + Kbeg + skc;
  const bf16* Bg;
  if constexpr (BN == 128)
    Bg = W + (size_t)(col0W + srow) * Kstride + Kbeg + skc;
  else
    Bg = W + (size_t)(col0W + (tid >> 2)) * Kstride + Kbeg + (size_t)(tid & 3) * 8;
  bf16* lAp = lA + tid * 8;
  bf16* lBp = lB + tid * 8;

  const int fr = lane & 15;
  const int q8 = (lane >> 4) * 8;

  for (int k0 = 0; k0 < Klen; k0 += 32) {
    __syncthreads();                          // WAR: previous iter's readers done
    gload16(Ag + k0, lAp);
    gload16(Ag + (size_t)64 * Kstride + k0, lAp + 2048);
    gload16(Bg + k0, lBp);
    if constexpr (BN == 128)
      gload16(Bg + (size_t)64 * Kstride + k0, lBp + 2048);
    __syncthreads();                          // vmcnt drain: staging visible

    bf16x8v af[4], bw[NJ];
#pragma unroll
    for (int i = 0; i < 4; i++)
      af[i] = *reinterpret_cast<const bf16x8v*>(&lA[(wr0 + i * 16 + fr) * 32 + q8]);
#pragma unroll
    for (int j = 0; j < NJ; j++)
      bw[j] = *reinterpret_cast<const bf16x8v*>(&lB[(wc0 + j * 16 + fr) * 32 + q8]);
#pragma unroll
    for (int i = 0; i < 4; i++)
#pragma unroll
      for (int j = 0; j < NJ; j++)
        acc[i][j] = __builtin_amdgcn_mfma_f32_16x16x32_bf16(af[i], bw[j], acc[i][j], 0, 0, 0);
  }

  const int quad = (lane >> 4) * 4;
#pragma unroll
  for (int j = 0; j < NJ; j++) {
    const int col = col0C + wc0 + j * 16 + fr;
    const float bvf = bias ? (float)bias[col] : 0.f;
#pragma unroll
    for (int i = 0; i < 4; i++) {
      const int r0 = row0 + wr0 + i * 16 + quad;
#pragma unroll
      for (int r = 0; r < 4; r++) {
        float v = acc[i][j][r] + bvf;
        if (EPI == 1) v = fmaxf(v, 0.f);
        C[(size_t)(r0 + r) * N + col] = (bf16)v;
      }
    }
  }
}

// NS = split-K factor. z-slice 0 writes C0 (with bias); slice 1 writes C1
// (no bias). Consumer (resid_ln) sums the partials for free.
template<int EPI, int BN, int NS>
__global__ __launch_bounds__(256) void gemm_bt(
    const bf16* __restrict__ A, const bf16* __restrict__ W,
    const bf16* __restrict__ bias, bf16* __restrict__ C0, bf16* __restrict__ C1,
    int N, int K)
{
  const int z  = (NS > 1) ? blockIdx.z : 0;
  const int Kp = K / NS;
  gemm_core<EPI, BN>(A, W, z == 0 ? bias : nullptr, z == 0 ? C0 : C1,
                     N, K, z * Kp, Kp,
                     blockIdx.x * 128, blockIdx.y * BN, blockIdx.y * BN);
}

// Fused Q/K/V projection: Wqkv is the contiguous [3072,1024] bf16 stack; one
// 768-block launch (3 blocks/CU). Each 128-col block lies in one output
// tensor (128 | 1024) -> bias/C selected per block (uniform).
__global__ __launch_bounds__(256) void gemm_qkv(
    const bf16* __restrict__ A, const bf16* __restrict__ Wqkv,
    const bf16* __restrict__ bq, const bf16* __restrict__ bk, const bf16* __restrict__ bv,
    bf16* __restrict__ Cq, bf16* __restrict__ Ck, bf16* __restrict__ Cv, int K)
{
  const int cg = blockIdx.y * 128;             // 0..2944, global W row
  const int t  = cg >> 10;
  const bf16* bias = (t == 0) ? bq : (t == 1) ? bk : bv;
  bf16*       C    = (t == 0) ? Cq : (t == 1) ? Ck : Cv;
  gemm_core<0, 128>(A, Wqkv, bias, C, 1024, K, 0, K,
                    blockIdx.x * 128, cg, cg & 1023);
}

// ---------------------------------------------------------------------------
// Band-sparse attention, MFMA version. One block = 32 query rows of one
// (b,h); band span <= 124, padded to 128 keys (K/V zero-filled past L).
// MASKING: both |s-t|<=WBAND AND c<L required (tail blocks: phantom columns
// pass the numeric band check -- round-1 failure).
// QK^T: M=32 N=128 K=64; PV: M=32 N=64 K=128 with V staged transposed.
// All LDS tiles XOR-swizzled so ds_read_b128 sits at the conflict floor.
// O may alias Q (Q staged to LDS first; disjoint block slices).
// ---------------------------------------------------------------------------
#define SKI(t, d)  ((((t) * 64) + (d)) ^ (((t) & 7) << 3))   // sQf / sKf (64-wide)
#define SVI(d, t)  ((((d) * 128) + (t)) ^ (((d) & 7) << 3))  // sVtf (128-wide)
#define SPI(q, c)  ((((q) * 128) + (c)) ^ (((q) & 7) << 3))  // sPf
#define SSI(q, c)  ((((q) * 128) + (c)) ^ (((q) & 7) << 2))  // sSf (f32)

__global__ __launch_bounds__(256) void attn_band(
    const bf16* __restrict__ Q, const bf16* __restrict__ Kp,
    const bf16* __restrict__ Vp, bf16* __restrict__ O)
{
  const int sblk = blockIdx.x;
  const int bh   = blockIdx.y;
  const int b    = bh >> 4;
  const int h    = bh & 15;
  const int s0   = sblk * 32;
  int tlo = s0 - WBAND;       if (tlo < 0) tlo = 0;
  int thi = s0 + 31 + WBAND;  if (thi > SEQL - 1) thi = SEQL - 1;
  const int L = thi - tlo + 1;           // 78..124

  __shared__ __align__(16) bf16  sQf[32 * 64];
  __shared__ __align__(16) bf16  sKf[128 * 64];
  __shared__ __align__(16) bf16  sVtf[64 * 128];
  __shared__ __align__(16) float sSf[32 * 128];
  __shared__ __align__(16) bf16  sPf[32 * 128];
  __shared__ float red1[32][8];
  __shared__ float red2[32][8];
  __shared__ float sInv[32];

  const int tid  = threadIdx.x;
  const int wave = tid >> 6;
  const int lane = tid & 63;
  const size_t base = ((size_t)b * SEQL) * EMBED + (size_t)h * HD;

  bf16x8v vz;
#pragma unroll
  for (int j = 0; j < 8; j++) vz[j] = (__bf16)0.f;

  // --- stage Q (32x64): one bf16x8 per thread
  {
    const int sl = tid >> 3, d0 = (tid & 7) * 8;
    *reinterpret_cast<bf16x8v*>(&sQf[SKI(sl, d0)]) =
        *reinterpret_cast<const bf16x8v*>(&Q[base + (size_t)(s0 + sl) * EMBED + d0]);
  }
  // --- stage K (128x64), zero-padded rows >= L
  for (int i = tid; i < 128 * 8; i += 256) {
    const int tl = i >> 3, d0 = (i & 7) * 8;
    bf16x8v v = vz;
    if (tl < L)
      v = *reinterpret_cast<const bf16x8v*>(&Kp[base + (size_t)(tlo + tl) * EMBED + d0]);
    *reinterpret_cast<bf16x8v*>(&sKf[SKI(tl, d0)]) = v;
  }
  // --- stage V transposed (d-major rows)
  for (int i = tid; i < 128 * 8; i += 256) {
    const int tl = i & 127, d0 = ((i >> 7) & 7) * 8;
    bf16x8v v = vz;
    if (tl < L)
      v = *reinterpret_cast<const bf16x8v*>(&Vp[base + (size_t)(tlo + tl) * EMBED + d0]);
#pragma unroll
    for (int j = 0; j < 8; j++)
      sVtf[SVI(d0 + j, tl)] = reinterpret_cast<const bf16*>(&v)[j];
  }
  __syncthreads();

  const int fr   = lane & 15;
  const int q8   = (lane >> 4) * 8;
  const int quad = (lane >> 4) * 4;

  // --- QK^T: wave w owns n-tiles {2w, 2w+1} x m-tiles {0,1}
  {
    f32x4v acc[2][2];
#pragma unroll
    for (int mi = 0; mi < 2; mi++)
#pragma unroll
      for (int nj = 0; nj < 2; nj++) acc[mi][nj] = (f32x4v){0.f, 0.f, 0.f, 0.f};
#pragma unroll
    for (int ks = 0; ks < 2; ks++) {
      bf16x8v a0 = *reinterpret_cast<const bf16x8v*>(&sQf[SKI(fr,      ks * 32 + q8)]);
      bf16x8v a1 = *reinterpret_cast<const bf16x8v*>(&sQf[SKI(16 + fr, ks * 32 + q8)]);
      bf16x8v b0 = *reinterpret_cast<const bf16x8v*>(&sKf[SKI((wave * 2    ) * 16 + fr, ks * 32 + q8)]);
      bf16x8v b1 = *reinterpret_cast<const bf16x8v*>(&sKf[SKI((wave * 2 + 1) * 16 + fr, ks * 32 + q8)]);
      acc[0][0] = __builtin_amdgcn_mfma_f32_16x16x32_bf16(a0, b0, acc[0][0], 0, 0, 0);
      acc[0][1] = __builtin_amdgcn_mfma_f32_16x16x32_bf16(a0, b1, acc[0][1], 0, 0, 0);
      acc[1][0] = __builtin_amdgcn_mfma_f32_16x16x32_bf16(a1, b0, acc[1][0], 0, 0, 0);
      acc[1][1] = __builtin_amdgcn_mfma_f32_16x16x32_bf16(a1, b1, acc[1][1], 0, 0, 0);
    }
#pragma unroll
    for (int nj = 0; nj < 2; nj++) {
      const int c = (wave * 2 + nj) * 16 + fr;
      const int t = tlo + c;
      const bool cvalid = (c < L);
#pragma unroll
      for (int mi = 0; mi < 2; mi++) {
#pragma unroll
        for (int r = 0; r < 4; r++) {
          const int row = mi * 16 + quad + r;
          int dd = (s0 + row) - t; if (dd < 0) dd = -dd;
          sSf[SSI(row, c)] = (cvalid && dd <= WBAND) ? acc[mi][nj][r] * 0.125f
                                                     : -1e30f;
        }
      }
    }
  }
  __syncthreads();

  // --- softmax over 128 cols, 8 partitions per row (row = tid&31)
  const int sl   = tid & 31;
  const int part = tid >> 5;
  float pmax = -1e30f;
#pragma unroll
  for (int k = 0; k < 16; k++) pmax = fmaxf(pmax, sSf[SSI(sl, part + 8 * k)]);
  red1[sl][part] = pmax;
  __syncthreads();
  float rmax = red1[sl][0];
#pragma unroll
  for (int p = 1; p < 8; p++) rmax = fmaxf(rmax, red1[sl][p]);

  float psum = 0.f;
#pragma unroll
  for (int k = 0; k < 16; k++) {
    const int c = part + 8 * k;
    float e = __expf(sSf[SSI(sl, c)] - rmax);   // masked/padded -> exactly 0
    sPf[SPI(sl, c)] = (bf16)e;
    psum += e;
  }
  red2[sl][part] = psum;
  __syncthreads();
  float rsum = 0.f;
#pragma unroll
  for (int p = 0; p < 8; p++) rsum += red2[sl][p];
  if (part == 0) sInv[sl] = 1.f / rsum;
  __syncthreads();                              // sPf + sInv ready

  // --- PV: O[32,64] = P[32,128] @ V. wave w: m-tile w>>1, n-tiles (w&1)*2+{0,1}
  {
    const int mi = wave >> 1;
    const int nb = (wave & 1) * 2;
    f32x4v acc[2];
    acc[0] = (f32x4v){0.f, 0.f, 0.f, 0.f};
    acc[1] = (f32x4v){0.f, 0.f, 0.f, 0.f};
#pragma unroll
    for (int ks = 0; ks < 4; ks++) {
      bf16x8v a  = *reinterpret_cast<const bf16x8v*>(&sPf[SPI(mi * 16 + fr, ks * 32 + q8)]);
      bf16x8v b0 = *reinterpret_cast<const bf16x8v*>(&sVtf[SVI((nb    ) * 16 + fr, ks * 32 + q8)]);
      bf16x8v b1 = *reinterpret_cast<const bf16x8v*>(&sVtf[SVI((nb + 1) * 16 + fr, ks * 32 + q8)]);
      acc[0] = __builtin_amdgcn_mfma_f32_16x16x32_bf16(a, b0, acc[0], 0, 0, 0);
      acc[1] = __builtin_amdgcn_mfma_f32_16x16x32_bf16(a, b1, acc[1], 0, 0, 0);
    }
#pragma unroll
    for (int nj = 0; nj < 2; nj++) {
      const int d = (nb + nj) * 16 + fr;
#pragma unroll
      for (int r = 0; r < 4; r++) {
        const int row = mi * 16 + quad + r;
        O[base + (size_t)(s0 + row) * EMBED + d] = (bf16)(acc[nj][r] * sInv[row]);
      }
    }
  }
}

// ---------------------------------------------------------------------------
// Fused residual add + LayerNorm. Sums TWO bf16 GEMM partials (split-K):
// v = x + y0 + y1. fp32 residual in/out (xin may == xf_out). y1 MAY alias
// xb_out: every thread reads only its own 4 elements before writing them,
// so the in-place overwrite is race-free. Optional final output keyed off
// dflag (fp32 world -> float*, bf16 world -> bf16*).
// ---------------------------------------------------------------------------
__global__ __launch_bounds__(256) void resid_ln(
    const float* xin, const bf16* __restrict__ y0, const bf16* y1,
    const bf16* __restrict__ g, const bf16* __restrict__ be,
    float* xf_out, bf16* xb_out,
    void* __restrict__ final_out, const int* __restrict__ dflag)
{
  __shared__ float red1[4];
  __shared__ float red2[4];
  const int row = blockIdx.x;
  const int tid = threadIdx.x;
  const size_t base = (size_t)row * EMBED + (size_t)tid * 4;

  f32x4v  xv  = *reinterpret_cast<const f32x4v*>(xin + base);
  bf16x4v yv0 = *reinterpret_cast<const bf16x4v*>(y0 + base);
  bf16x4v yv1 = *reinterpret_cast<const bf16x4v*>(y1 + base);
  float v[4];
#pragma unroll
  for (int j = 0; j < 4; j++) v[j] = xv[j] + (float)yv0[j] + (float)yv1[j];

  float s = v[0] + v[1] + v[2] + v[3];
#pragma unroll
  for (int off = 32; off > 0; off >>= 1) s += __shfl_down(s, off, 64);
  if ((tid & 63) == 0) red1[tid >> 6] = s;
  __syncthreads();
  const float mu = (red1[0] + red1[1] + red1[2] + red1[3]) * (1.f / EMBED);

  float sq = 0.f;
#pragma unroll
  for (int j = 0; j < 4; j++) { const float d = v[j] - mu; sq += d * d; }
#pragma unroll
  for (int off = 32; off > 0; off >>= 1) sq += __shfl_down(sq, off, 64);
  if ((tid & 63) == 0) red2[tid >> 6] = sq;
  __syncthreads();
  const float rstd = rsqrtf((red2[0] + red2[1] + red2[2] + red2[3]) * (1.f / EMBED) + LN_EPS);

  bf16x4v gv = *reinterpret_cast<const bf16x4v*>(g + (size_t)tid * 4);
  bf16x4v bv = *reinterpret_cast<const bf16x4v*>(be + (size_t)tid * 4);
  f32x4v of;
  bf16x4v ov;
#pragma unroll
  for (int j = 0; j < 4; j++) {
    of[j] = (v[j] - mu) * rstd * (float)gv[j] + (float)bv[j];
    ov[j] = (__bf16)of[j];
  }
  *reinterpret_cast<f32x4v*>(xf_out + base) = of;
  *reinterpret_cast<bf16x4v*>(xb_out + base) = ov;
  if (final_out) {
    if (*dflag)
      *reinterpret_cast<bf16x4v*>((bf16*)final_out + base) = ov;
    else
      *reinterpret_cast<f32x4v*>((float*)final_out + base) = of;
  }
}

// ---------------------------------------------------------------------------
// ws layout (89 MB peak, liveness-verified incl. split-K partials):
//  [0,4K) flag | [4K,~112K) bf16 param copies
//  [ 1,17) xf fp32 residual | [17,25) xb bf16 activation
//  [25,33) q (=ao alias)    | [33,41) kk | [41,49) vv
//  [25,57) hh 32MB (FF1 out; q/kk/vv dead by FF1)
//  [57,65) y bf16           | [65,89) wbf bf16 weights (per layer)
// split-K partials (bf16, 8 MB each, reuse dead regions):
//  O-proj: slice0 -> kk [33,41), slice1 -> vv [41,49)   (dead after attn;
//          disjoint from input ao=q [25,33))
//  FF2:    slice0 -> y  [57,65), slice1 -> xb [17,25)   (xb dead during FF2;
//          disjoint from input hh [25,57); LN2 re-writes xb in place, safe)
// ---------------------------------------------------------------------------
extern "C" void kernel_launch(void* const* d_in, const int* in_sizes, int n_in,
                              void* d_out, int out_size, void* d_ws, size_t ws_size,
                              hipStream_t stream)
{
  char* ws = (char*)d_ws;
  const size_t MB = 1024 * 1024;
  int*   flag = (int*)ws;
  bf16*  pp   = (bf16*)(ws + 4096);
  float* xf   = (float*)(ws + 1 * MB);
  bf16*  xb   = (bf16*)(ws + 17 * MB);
  bf16*  q    = (bf16*)(ws + 25 * MB);
  bf16*  kk   = (bf16*)(ws + 33 * MB);
  bf16*  vv   = (bf16*)(ws + 41 * MB);
  bf16*  ao   = q;
  bf16*  hh   = (bf16*)(ws + 25 * MB);     // 32 MB
  bf16*  y    = (bf16*)(ws + 57 * MB);
  bf16*  wbf  = (bf16*)(ws + 65 * MB);     // 24 MB bf16 weights (per layer)

  // bf16 param-copy element offsets within pp
  bf16* pbq = pp;            bf16* pbk = pp + 4096;  bf16* pbv = pp + 8192;
  bf16* pbo = pp + 12288;    bf16* pb1 = pp + 16384; bf16* pb2 = pp + 32768;
  bf16* pg1 = pp + 36864;    bf16* pe1 = pp + 40960;
  bf16* pg2 = pp + 45056;    bf16* pe2 = pp + 49152;

  detect_dtype<<<1, 256, 0, stream>>>((const unsigned int*)d_in[0], flag);

  cast_param<<<16, 256, 0, stream>>>(d_in[2],  pbq, 4096,  flag);
  cast_param<<<16, 256, 0, stream>>>(d_in[4],  pbk, 4096,  flag);
  cast_param<<<16, 256, 0, stream>>>(d_in[6],  pbv, 4096,  flag);
  cast_param<<<16, 256, 0, stream>>>(d_in[8],  pbo, 4096,  flag);
  cast_param<<<64, 256, 0, stream>>>(d_in[10], pb1, 16384, flag);
  cast_param<<<16, 256, 0, stream>>>(d_in[12], pb2, 4096,  flag);
  cast_param<<<16, 256, 0, stream>>>(d_in[13], pg1, 4096,  flag);
  cast_param<<<16, 256, 0, stream>>>(d_in[14], pe1, 4096,  flag);
  cast_param<<<16, 256, 0, stream>>>(d_in[15], pg2, 4096,  flag);
  cast_param<<<16, 256, 0, stream>>>(d_in[16], pe2, 4096,  flag);

  cast_in<<<dim3((NTOK * EMBED) / 256), 256, 0, stream>>>(
      d_in[0], xf, xb, NTOK * EMBED, flag);

  for (int l = 0; l < 4; l++) {
    // convert this layer's weights to bf16 (Wq|Wk|Wv stacked = fused QKV W)
    cast_weights<<<6144, 256, 0, stream>>>(
        d_in[1], d_in[3], d_in[5], d_in[7], d_in[9], d_in[11],
        (size_t)l * 1048576, (size_t)l * 4194304, wbf, flag);

    gemm_qkv<<<dim3(32, 24), 256, 0, stream>>>(
        xb, wbf, pbq + l * 1024, pbk + l * 1024, pbv + l * 1024,
        q, kk, vv, EMBED);
    attn_band<<<dim3(SEQL / 32, 32), 256, 0, stream>>>(q, kk, vv, ao);
    // O-proj: split-K x2 -> partials in dead kk/vv (1024 blocks = 4/CU)
    gemm_bt<0, 64, 2><<<dim3(32, 16, 2), 256, 0, stream>>>(
        ao, wbf + 3 * 1048576, pbo + l * 1024, kk, vv, EMBED, EMBED);
    resid_ln<<<dim3(NTOK), 256, 0, stream>>>(
        xf, kk, vv, pg1 + l * 1024, pe1 + l * 1024, xf, xb, nullptr, flag);
    gemm_bt<1, 128, 1><<<dim3(32, 32, 1), 256, 0, stream>>>(
        xb, wbf + 4 * 1048576, pb1 + l * 4096, hh, nullptr, FF_DIM, EMBED);
    // FF2: split-K x2 -> partials in y + dead xb (1024 blocks = 4/CU)
    gemm_bt<0, 64, 2><<<dim3(32, 16, 2), 256, 0, stream>>>(
        hh, wbf + 8 * 1048576, pb2 + l * 1024, y, xb, EMBED, FF_DIM);
    resid_ln<<<dim3(NTOK), 256, 0, stream>>>(
        xf, y, xb, pg2 + l * 1024, pe2 + l * 1024, xf, xb,
        l == 3 ? d_out : nullptr, flag);
  }
}

// Round 7
// 1073.821 us; speedup vs baseline: 1.6017x; 1.0545x over previous
//
#include <hip/hip_runtime.h>
#include <hip/hip_bf16.h>

using bf16 = __hip_bfloat16;
typedef __bf16 bf16x8v __attribute__((ext_vector_type(8)));
typedef __bf16 bf16x4v __attribute__((ext_vector_type(4)));
typedef float f32x4v __attribute__((ext_vector_type(4)));

#define EMBED 1024
#define FF_DIM 4096
#define NTOK 4096          // BATCH * SEQ
#define SEQL 2048
#define HD 64
#define WBAND 46           // ceil(sqrt(2048))
#define LN_EPS 1e-5f

// async global->LDS, 16B per lane. LDS dest must be wave-uniform base +
// lane*16B (m104/m108); all staging layouts here use lds_off = tid*8 bf16
// elems = wave-uniform + lane*16B. Addresses are STATIC (single buffer) --
// round-4's runtime-indexed double buffer defeated the scheduler.
__device__ __forceinline__ void gload16(const bf16* g, bf16* l)
{
  __builtin_amdgcn_global_load_lds(
      (const __attribute__((address_space(1))) void*)g,
      (__attribute__((address_space(3))) void*)l, 16, 0, 0);
}

// ---------------------------------------------------------------------------
// Input-dtype detection: flag 1 = bf16 inputs, 0 = fp32 inputs.
// ---------------------------------------------------------------------------
__global__ __launch_bounds__(256) void detect_dtype(
    const unsigned int* __restrict__ xw, int* __restrict__ flag)
{
  __shared__ int votes[256];
  int v = 0;
#pragma unroll
  for (int j = 0; j < 4; j++) {
    unsigned int w = xw[1 + threadIdx.x * 4 + j];
    unsigned int e = (w >> 7) & 0xFFu;          // low halfword's bf16 exponent
    v += (e == 0u || (e >= 0x58u && e <= 0x88u)) ? 1 : 0;
  }
  votes[threadIdx.x] = v;
  __syncthreads();
  if (threadIdx.x == 0) {
    int s = 0;
    for (int i = 0; i < 256; i++) s += votes[i];
    *flag = (s > 512) ? 1 : 0;
  }
}

// generic param cast -> bf16 internal copy (biases / LN gains), flag-branched
__global__ __launch_bounds__(256) void cast_param(
    const void* __restrict__ src, bf16* __restrict__ dst, int n,
    const int* __restrict__ dflag)
{
  const int is_bf16 = *dflag;
  for (int i = blockIdx.x * 256 + threadIdx.x; i < n; i += gridDim.x * 256)
    dst[i] = is_bf16 ? ((const bf16*)src)[i] : (bf16)(((const float*)src)[i]);
}

// x -> fp32 residual stream + bf16 activation copy, flag-branched
__global__ __launch_bounds__(256) void cast_in(
    const void* __restrict__ x, float* __restrict__ xf,
    bf16* __restrict__ xb, int n, const int* __restrict__ dflag)
{
  const int is_bf16 = *dflag;
  const int i = blockIdx.x * 256 + threadIdx.x;
  if (i < n) {
    float v = is_bf16 ? (float)((const bf16*)x)[i] : ((const float*)x)[i];
    xf[i] = v;
    xb[i] = (bf16)v;
  }
}

// ---------------------------------------------------------------------------
// Per-layer weight conversion -> contiguous bf16 scratch (24 MB):
//  [0,1M) Wq  [1M,2M) Wk  [2M,3M) Wv  [3M,4M) Wo  [4M,8M) W1  [8M,12M) W2
// Wq/Wk/Wv stacked = one [3072,1024] matrix for the fused QKV GEMM.
// ---------------------------------------------------------------------------
__global__ __launch_bounds__(256) void cast_weights(
    const void* __restrict__ wq, const void* __restrict__ wk,
    const void* __restrict__ wv, const void* __restrict__ wo,
    const void* __restrict__ w1, const void* __restrict__ w2,
    size_t off_ee, size_t off_fe, bf16* __restrict__ dst,
    const int* __restrict__ dflag)
{
  const int is_bf16 = *dflag;
  const int c = blockIdx.x * 256 + threadIdx.x;     // 1,572,864 chunks of 8
  const size_t i = (size_t)c * 8;
  const void* src;
  size_t si;
  if (i < 4194304) {                                // four EMBEDxEMBED tensors
    const int t = (int)(i >> 20);
    src = (t == 0) ? wq : (t == 1) ? wk : (t == 2) ? wv : wo;
    si  = off_ee + (i & 1048575);
  } else if (i < 8388608) { src = w1; si = off_fe + (i - 4194304); }
  else                    { src = w2; si = off_fe + (i - 8388608); }
  bf16x8v o;
  if (is_bf16) {
    o = *reinterpret_cast<const bf16x8v*>((const bf16*)src + si);
  } else {
    f32x4v a = *reinterpret_cast<const f32x4v*>((const float*)src + si);
    f32x4v b = *reinterpret_cast<const f32x4v*>((const float*)src + si + 4);
#pragma unroll
    for (int j = 0; j < 4; j++) { o[j] = (__bf16)a[j]; o[j + 4] = (__bf16)b[j]; }
  }
  *reinterpret_cast<bf16x8v*>(dst + i) = o;
}

// ---------------------------------------------------------------------------
// NT GEMM core: C[128 x BN] = A[M,Kslice] @ W[N,Kslice]^T (+bias).
// Round-7 changes vs the verified m97-style loop:
//  * BK=64 (2 barrier drains per 32 MFMA instead of 16): LDS holds the two
//    k-halves as separate [row][32] sub-tiles, so the gload_lds destination
//    stays LINEAR (tid*16B per issue) and fragment reads keep the verified
//    row*32+q8 addressing -- no swizzle, all addresses static.
//  * Vectorized epilogue: acc+bias(+relu) -> LDS (chunk-XOR spread on
//    (row>>2)&7), barrier, read back bf16x8, 16B/lane coalesced stores.
//    Replaces 64 scalar stride-N 2B stores (round-6: WRITE_SIZE 1.5x ideal).
// Kstride: row stride of A and W (full K). [Kbeg,Kbeg+Klen): K-slice
// (Klen % 64 == 0 for all call sites). bias==nullptr for split-K slice 1.
// Verified MFMA layouts (m89/m91): A/B-frag row=lane&15,k=(lane>>4)*8+j;
// C/D col=lane&15, row=(lane>>4)*4+reg.  EPI: 1 = relu.
// ---------------------------------------------------------------------------
#define SWZ(row) ((((row) >> 2) & 7) << 3)     // chunk-granular col XOR

template<int EPI, int BN>
__device__ __forceinline__ void gemm_core(
    const bf16* __restrict__ A, const bf16* __restrict__ W,
    const bf16* __restrict__ bias, bf16* __restrict__ C,
    int N, int Kstride, int Kbeg, int Klen,
    int row0, int col0W, int col0C)
{
  constexpr int NJ    = BN / 32;
  constexpr int STAGE = 128 * 64 + BN * 64;          // elems
  constexpr int TOT   = (STAGE > 128 * BN) ? STAGE : 128 * BN;
  __shared__ __align__(16) bf16 smem[TOT];
  bf16* lA = smem;                 // [2 halves][128 rows][32]
  bf16* lB = smem + 128 * 64;      // [2 halves][BN rows][32]

  const int tid  = threadIdx.x;
  const int wave = tid >> 6;
  const int lane = tid & 63;
  const int wr0  = (wave >> 1) * 64;
  const int wc0  = (wave & 1) * (BN / 2);

  f32x4v acc[4][NJ];
#pragma unroll
  for (int i = 0; i < 4; i++)
#pragma unroll
    for (int j = 0; j < NJ; j++) acc[i][j] = (f32x4v){0.f, 0.f, 0.f, 0.f};

  // staging map: thread t -> row = t/4 (within a 64-row block), kchunk=(t&3)*8;
  // issue (h = k-half, rb = 64-row block) -> lds off = h*half + rb*2048 + t*8
  // (per-wave linear: wave-uniform base + lane*16B).
  const int rowa = tid >> 2;
  const int kca  = (tid & 3) * 8;
  const bf16* Ag = A + (size_t)(row0 + rowa) * Kstride + Kbeg + kca;
  const bf16* Bg = W + (size_t)(col0W + rowa) * Kstride + Kbeg + kca;
  bf16* lAp = lA + tid * 8;
  bf16* lBp = lB + tid * 8;

  const int fr = lane & 15;
  const int q8 = (lane >> 4) * 8;

  for (int k0 = 0; k0 < Klen; k0 += 64) {
    __syncthreads();                          // WAR: previous iter's readers done
#pragma unroll
    for (int h = 0; h < 2; h++) {
#pragma unroll
      for (int rb = 0; rb < 2; rb++)
        gload16(Ag + (size_t)rb * 64 * Kstride + k0 + h * 32,
                lAp + h * 4096 + rb * 2048);
#pragma unroll
      for (int rb = 0; rb < BN / 64; rb++)
        gload16(Bg + (size_t)rb * 64 * Kstride + k0 + h * 32,
                lBp + h * (BN * 32) + rb * 2048);
    }
    __syncthreads();                          // vmcnt drain: staging visible

#pragma unroll
    for (int ks = 0; ks < 2; ks++) {
      bf16x8v af[4], bw[NJ];
#pragma unroll
      for (int i = 0; i < 4; i++)
        af[i] = *reinterpret_cast<const bf16x8v*>(
            &lA[ks * 4096 + (wr0 + i * 16 + fr) * 32 + q8]);
#pragma unroll
      for (int j = 0; j < NJ; j++)
        bw[j] = *reinterpret_cast<const bf16x8v*>(
            &lB[ks * (BN * 32) + (wc0 + j * 16 + fr) * 32 + q8]);
#pragma unroll
      for (int i = 0; i < 4; i++)
#pragma unroll
        for (int j = 0; j < NJ; j++)
          acc[i][j] = __builtin_amdgcn_mfma_f32_16x16x32_bf16(af[i], bw[j], acc[i][j], 0, 0, 0);
    }
  }

  // ---- epilogue: acc -> LDS (swizzled) -> coalesced 16B global stores ----
  const int quad = (lane >> 4) * 4;
  __syncthreads();                            // all LDS frag reads complete
#pragma unroll
  for (int j = 0; j < NJ; j++) {
    const int col = wc0 + j * 16 + fr;        // tile-local col
    const float bvf = bias ? (float)bias[col0C + col] : 0.f;
#pragma unroll
    for (int i = 0; i < 4; i++) {
#pragma unroll
      for (int r = 0; r < 4; r++) {
        const int row = wr0 + i * 16 + quad + r;
        float v = acc[i][j][r] + bvf;
        if (EPI == 1) v = fmaxf(v, 0.f);
        smem[row * BN + (col ^ SWZ(row))] = (bf16)v;
      }
    }
  }
  __syncthreads();
  constexpr int CPR = BN / 8;                 // 16B chunks per row
  constexpr int RPP = 256 / CPR;              // rows per pass
  const int erow = tid / CPR;
  const int ec8  = (tid % CPR) * 8;
#pragma unroll
  for (int p = 0; p < 128 / RPP; p++) {
    const int row = p * RPP + erow;
    bf16x8v v = *reinterpret_cast<const bf16x8v*>(
        &smem[row * BN + (ec8 ^ SWZ(row))]);
    *reinterpret_cast<bf16x8v*>(&C[(size_t)(row0 + row) * N + col0C + ec8]) = v;
  }
}

// NS = split-K factor. z-slice 0 writes C0 (with bias); slice 1 writes C1
// (no bias). Consumer (resid_ln) sums the partials for free.
template<int EPI, int BN, int NS>
__global__ __launch_bounds__(256) void gemm_bt(
    const bf16* __restrict__ A, const bf16* __restrict__ W,
    const bf16* __restrict__ bias, bf16* __restrict__ C0, bf16* __restrict__ C1,
    int N, int K)
{
  const int z  = (NS > 1) ? blockIdx.z : 0;
  const int Kp = K / NS;
  gemm_core<EPI, BN>(A, W, z == 0 ? bias : nullptr, z == 0 ? C0 : C1,
                     N, K, z * Kp, Kp,
                     blockIdx.x * 128, blockIdx.y * BN, blockIdx.y * BN);
}

// Fused Q/K/V projection: Wqkv is the contiguous [3072,1024] bf16 stack; one
// 768-block launch (3 blocks/CU). Each 128-col block lies in one output
// tensor (128 | 1024) -> bias/C selected per block (uniform).
__global__ __launch_bounds__(256) void gemm_qkv(
    const bf16* __restrict__ A, const bf16* __restrict__ Wqkv,
    const bf16* __restrict__ bq, const bf16* __restrict__ bk, const bf16* __restrict__ bv,
    bf16* __restrict__ Cq, bf16* __restrict__ Ck, bf16* __restrict__ Cv, int K)
{
  const int cg = blockIdx.y * 128;             // 0..2944, global W row
  const int t  = cg >> 10;
  const bf16* bias = (t == 0) ? bq : (t == 1) ? bk : bv;
  bf16*       C    = (t == 0) ? Cq : (t == 1) ? Ck : Cv;
  gemm_core<0, 128>(A, Wqkv, bias, C, 1024, K, 0, K,
                    blockIdx.x * 128, cg, cg & 1023);
}

// ---------------------------------------------------------------------------
// Band-sparse attention, MFMA version. One block = 32 query rows of one
// (b,h); band span <= 124, padded to 128 keys (K/V zero-filled past L).
// MASKING: both |s-t|<=WBAND AND c<L required (tail blocks: phantom columns
// pass the numeric band check -- round-1 failure).
// QK^T: M=32 N=128 K=64; PV: M=32 N=64 K=128 with V staged transposed.
// All LDS tiles XOR-swizzled so ds_read_b128 sits at the conflict floor.
// O may alias Q (Q staged to LDS first; disjoint block slices).
// ---------------------------------------------------------------------------
#define SKI(t, d)  ((((t) * 64) + (d)) ^ (((t) & 7) << 3))   // sQf / sKf (64-wide)
#define SVI(d, t)  ((((d) * 128) + (t)) ^ (((d) & 7) << 3))  // sVtf (128-wide)
#define SPI(q, c)  ((((q) * 128) + (c)) ^ (((q) & 7) << 3))  // sPf
#define SSI(q, c)  ((((q) * 128) + (c)) ^ (((q) & 7) << 2))  // sSf (f32)

__global__ __launch_bounds__(256) void attn_band(
    const bf16* __restrict__ Q, const bf16* __restrict__ Kp,
    const bf16* __restrict__ Vp, bf16* __restrict__ O)
{
  const int sblk = blockIdx.x;
  const int bh   = blockIdx.y;
  const int b    = bh >> 4;
  const int h    = bh & 15;
  const int s0   = sblk * 32;
  int tlo = s0 - WBAND;       if (tlo < 0) tlo = 0;
  int thi = s0 + 31 + WBAND;  if (thi > SEQL - 1) thi = SEQL - 1;
  const int L = thi - tlo + 1;           // 78..124

  __shared__ __align__(16) bf16  sQf[32 * 64];
  __shared__ __align__(16) bf16  sKf[128 * 64];
  __shared__ __align__(16) bf16  sVtf[64 * 128];
  __shared__ __align__(16) float sSf[32 * 128];
  __shared__ __align__(16) bf16  sPf[32 * 128];
  __shared__ float red1[32][8];
  __shared__ float red2[32][8];
  __shared__ float sInv[32];

  const int tid  = threadIdx.x;
  const int wave = tid >> 6;
  const int lane = tid & 63;
  const size_t base = ((size_t)b * SEQL) * EMBED + (size_t)h * HD;

  bf16x8v vz;
#pragma unroll
  for (int j = 0; j < 8; j++) vz[j] = (__bf16)0.f;

  // --- stage Q (32x64): one bf16x8 per thread
  {
    const int sl = tid >> 3, d0 = (tid & 7) * 8;
    *reinterpret_cast<bf16x8v*>(&sQf[SKI(sl, d0)]) =
        *reinterpret_cast<const bf16x8v*>(&Q[base + (size_t)(s0 + sl) * EMBED + d0]);
  }
  // --- stage K (128x64), zero-padded rows >= L
  for (int i = tid; i < 128 * 8; i += 256) {
    const int tl = i >> 3, d0 = (i & 7) * 8;
    bf16x8v v = vz;
    if (tl < L)
      v = *reinterpret_cast<const bf16x8v*>(&Kp[base + (size_t)(tlo + tl) * EMBED + d0]);
    *reinterpret_cast<bf16x8v*>(&sKf[SKI(tl, d0)]) = v;
  }
  // --- stage V transposed (d-major rows)
  for (int i = tid; i < 128 * 8; i += 256) {
    const int tl = i & 127, d0 = ((i >> 7) & 7) * 8;
    bf16x8v v = vz;
    if (tl < L)
      v = *reinterpret_cast<const bf16x8v*>(&Vp[base + (size_t)(tlo + tl) * EMBED + d0]);
#pragma unroll
    for (int j = 0; j < 8; j++)
      sVtf[SVI(d0 + j, tl)] = reinterpret_cast<const bf16*>(&v)[j];
  }
  __syncthreads();

  const int fr   = lane & 15;
  const int q8   = (lane >> 4) * 8;
  const int quad = (lane >> 4) * 4;

  // --- QK^T: wave w owns n-tiles {2w, 2w+1} x m-tiles {0,1}
  {
    f32x4v acc[2][2];
#pragma unroll
    for (int mi = 0; mi < 2; mi++)
#pragma unroll
      for (int nj = 0; nj < 2; nj++) acc[mi][nj] = (f32x4v){0.f, 0.f, 0.f, 0.f};
#pragma unroll
    for (int ks = 0; ks < 2; ks++) {
      bf16x8v a0 = *reinterpret_cast<const bf16x8v*>(&sQf[SKI(fr,      ks * 32 + q8)]);
      bf16x8v a1 = *reinterpret_cast<const bf16x8v*>(&sQf[SKI(16 + fr, ks * 32 + q8)]);
      bf16x8v b0 = *reinterpret_cast<const bf16x8v*>(&sKf[SKI((wave * 2    ) * 16 + fr, ks * 32 + q8)]);
      bf16x8v b1 = *reinterpret_cast<const bf16x8v*>(&sKf[SKI((wave * 2 + 1) * 16 + fr, ks * 32 + q8)]);
      acc[0][0] = __builtin_amdgcn_mfma_f32_16x16x32_bf16(a0, b0, acc[0][0], 0, 0, 0);
      acc[0][1] = __builtin_amdgcn_mfma_f32_16x16x32_bf16(a0, b1, acc[0][1], 0, 0, 0);
      acc[1][0] = __builtin_amdgcn_mfma_f32_16x16x32_bf16(a1, b0, acc[1][0], 0, 0, 0);
      acc[1][1] = __builtin_amdgcn_mfma_f32_16x16x32_bf16(a1, b1, acc[1][1], 0, 0, 0);
    }
#pragma unroll
    for (int nj = 0; nj < 2; nj++) {
      const int c = (wave * 2 + nj) * 16 + fr;
      const int t = tlo + c;
      const bool cvalid = (c < L);
#pragma unroll
      for (int mi = 0; mi < 2; mi++) {
#pragma unroll
        for (int r = 0; r < 4; r++) {
          const int row = mi * 16 + quad + r;
          int dd = (s0 + row) - t; if (dd < 0) dd = -dd;
          sSf[SSI(row, c)] = (cvalid && dd <= WBAND) ? acc[mi][nj][r] * 0.125f
                                                     : -1e30f;
        }
      }
    }
  }
  __syncthreads();

  // --- softmax over 128 cols, 8 partitions per row (row = tid&31)
  const int sl   = tid & 31;
  const int part = tid >> 5;
  float pmax = -1e30f;
#pragma unroll
  for (int k = 0; k < 16; k++) pmax = fmaxf(pmax, sSf[SSI(sl, part + 8 * k)]);
  red1[sl][part] = pmax;
  __syncthreads();
  float rmax = red1[sl][0];
#pragma unroll
  for (int p = 1; p < 8; p++) rmax = fmaxf(rmax, red1[sl][p]);

  float psum = 0.f;
#pragma unroll
  for (int k = 0; k < 16; k++) {
    const int c = part + 8 * k;
    float e = __expf(sSf[SSI(sl, c)] - rmax);   // masked/padded -> exactly 0
    sPf[SPI(sl, c)] = (bf16)e;
    psum += e;
  }
  red2[sl][part] = psum;
  __syncthreads();
  float rsum = 0.f;
#pragma unroll
  for (int p = 0; p < 8; p++) rsum += red2[sl][p];
  if (part == 0) sInv[sl] = 1.f / rsum;
  __syncthreads();                              // sPf + sInv ready

  // --- PV: O[32,64] = P[32,128] @ V. wave w: m-tile w>>1, n-tiles (w&1)*2+{0,1}
  {
    const int mi = wave >> 1;
    const int nb = (wave & 1) * 2;
    f32x4v acc[2];
    acc[0] = (f32x4v){0.f, 0.f, 0.f, 0.f};
    acc[1] = (f32x4v){0.f, 0.f, 0.f, 0.f};
#pragma unroll
    for (int ks = 0; ks < 4; ks++) {
      bf16x8v a  = *reinterpret_cast<const bf16x8v*>(&sPf[SPI(mi * 16 + fr, ks * 32 + q8)]);
      bf16x8v b0 = *reinterpret_cast<const bf16x8v*>(&sVtf[SVI((nb    ) * 16 + fr, ks * 32 + q8)]);
      bf16x8v b1 = *reinterpret_cast<const bf16x8v*>(&sVtf[SVI((nb + 1) * 16 + fr, ks * 32 + q8)]);
      acc[0] = __builtin_amdgcn_mfma_f32_16x16x32_bf16(a, b0, acc[0], 0, 0, 0);
      acc[1] = __builtin_amdgcn_mfma_f32_16x16x32_bf16(a, b1, acc[1], 0, 0, 0);
    }
#pragma unroll
    for (int nj = 0; nj < 2; nj++) {
      const int d = (nb + nj) * 16 + fr;
#pragma unroll
      for (int r = 0; r < 4; r++) {
        const int row = mi * 16 + quad + r;
        O[base + (size_t)(s0 + row) * EMBED + d] = (bf16)(acc[nj][r] * sInv[row]);
      }
    }
  }
}

// ---------------------------------------------------------------------------
// Fused residual add + LayerNorm. Sums TWO bf16 GEMM partials (split-K):
// v = x + y0 + y1. fp32 residual in/out (xin may == xf_out). y1 MAY alias
// xb_out (each thread reads its own 4 elems before writing them). Optional
// final output keyed off dflag (fp32 world -> float*, bf16 world -> bf16*).
// ---------------------------------------------------------------------------
__global__ __launch_bounds__(256) void resid_ln(
    const float* xin, const bf16* __restrict__ y0, const bf16* y1,
    const bf16* __restrict__ g, const bf16* __restrict__ be,
    float* xf_out, bf16* xb_out,
    void* __restrict__ final_out, const int* __restrict__ dflag)
{
  __shared__ float red1[4];
  __shared__ float red2[4];
  const int row = blockIdx.x;
  const int tid = threadIdx.x;
  const size_t base = (size_t)row * EMBED + (size_t)tid * 4;

  f32x4v  xv  = *reinterpret_cast<const f32x4v*>(xin + base);
  bf16x4v yv0 = *reinterpret_cast<const bf16x4v*>(y0 + base);
  bf16x4v yv1 = *reinterpret_cast<const bf16x4v*>(y1 + base);
  float v[4];
#pragma unroll
  for (int j = 0; j < 4; j++) v[j] = xv[j] + (float)yv0[j] + (float)yv1[j];

  float s = v[0] + v[1] + v[2] + v[3];
#pragma unroll
  for (int off = 32; off > 0; off >>= 1) s += __shfl_down(s, off, 64);
  if ((tid & 63) == 0) red1[tid >> 6] = s;
  __syncthreads();
  const float mu = (red1[0] + red1[1] + red1[2] + red1[3]) * (1.f / EMBED);

  float sq = 0.f;
#pragma unroll
  for (int j = 0; j < 4; j++) { const float d = v[j] - mu; sq += d * d; }
#pragma unroll
  for (int off = 32; off > 0; off >>= 1) sq += __shfl_down(sq, off, 64);
  if ((tid & 63) == 0) red2[tid >> 6] = sq;
  __syncthreads();
  const float rstd = rsqrtf((red2[0] + red2[1] + red2[2] + red2[3]) * (1.f / EMBED) + LN_EPS);

  bf16x4v gv = *reinterpret_cast<const bf16x4v*>(g + (size_t)tid * 4);
  bf16x4v bv = *reinterpret_cast<const bf16x4v*>(be + (size_t)tid * 4);
  f32x4v of;
  bf16x4v ov;
#pragma unroll
  for (int j = 0; j < 4; j++) {
    of[j] = (v[j] - mu) * rstd * (float)gv[j] + (float)bv[j];
    ov[j] = (__bf16)of[j];
  }
  *reinterpret_cast<f32x4v*>(xf_out + base) = of;
  *reinterpret_cast<bf16x4v*>(xb_out + base) = ov;
  if (final_out) {
    if (*dflag)
      *reinterpret_cast<bf16x4v*>((bf16*)final_out + base) = ov;
    else
      *reinterpret_cast<f32x4v*>((float*)final_out + base) = of;
  }
}

// ---------------------------------------------------------------------------
// ws layout (89 MB peak, liveness-verified incl. split-K partials):
//  [0,4K) flag | [4K,~112K) bf16 param copies
//  [ 1,17) xf fp32 residual | [17,25) xb bf16 activation
//  [25,33) q (=ao alias)    | [33,41) kk | [41,49) vv
//  [25,57) hh 32MB (FF1 out; q/kk/vv dead by FF1)
//  [57,65) y bf16           | [65,89) wbf bf16 weights (per layer)
// split-K partials (bf16, 8 MB each, reuse dead regions):
//  O-proj: slice0 -> kk, slice1 -> vv   (dead after attn; disjoint from ao=q)
//  FF2:    slice0 -> y,  slice1 -> xb   (xb dead during FF2; LN2 rewrites it)
// ---------------------------------------------------------------------------
extern "C" void kernel_launch(void* const* d_in, const int* in_sizes, int n_in,
                              void* d_out, int out_size, void* d_ws, size_t ws_size,
                              hipStream_t stream)
{
  char* ws = (char*)d_ws;
  const size_t MB = 1024 * 1024;
  int*   flag = (int*)ws;
  bf16*  pp   = (bf16*)(ws + 4096);
  float* xf   = (float*)(ws + 1 * MB);
  bf16*  xb   = (bf16*)(ws + 17 * MB);
  bf16*  q    = (bf16*)(ws + 25 * MB);
  bf16*  kk   = (bf16*)(ws + 33 * MB);
  bf16*  vv   = (bf16*)(ws + 41 * MB);
  bf16*  ao   = q;
  bf16*  hh   = (bf16*)(ws + 25 * MB);     // 32 MB
  bf16*  y    = (bf16*)(ws + 57 * MB);
  bf16*  wbf  = (bf16*)(ws + 65 * MB);     // 24 MB bf16 weights (per layer)

  // bf16 param-copy element offsets within pp
  bf16* pbq = pp;            bf16* pbk = pp + 4096;  bf16* pbv = pp + 8192;
  bf16* pbo = pp + 12288;    bf16* pb1 = pp + 16384; bf16* pb2 = pp + 32768;
  bf16* pg1 = pp + 36864;    bf16* pe1 = pp + 40960;
  bf16* pg2 = pp + 45056;    bf16* pe2 = pp + 49152;

  detect_dtype<<<1, 256, 0, stream>>>((const unsigned int*)d_in[0], flag);

  cast_param<<<16, 256, 0, stream>>>(d_in[2],  pbq, 4096,  flag);
  cast_param<<<16, 256, 0, stream>>>(d_in[4],  pbk, 4096,  flag);
  cast_param<<<16, 256, 0, stream>>>(d_in[6],  pbv, 4096,  flag);
  cast_param<<<16, 256, 0, stream>>>(d_in[8],  pbo, 4096,  flag);
  cast_param<<<64, 256, 0, stream>>>(d_in[10], pb1, 16384, flag);
  cast_param<<<16, 256, 0, stream>>>(d_in[12], pb2, 4096,  flag);
  cast_param<<<16, 256, 0, stream>>>(d_in[13], pg1, 4096,  flag);
  cast_param<<<16, 256, 0, stream>>>(d_in[14], pe1, 4096,  flag);
  cast_param<<<16, 256, 0, stream>>>(d_in[15], pg2, 4096,  flag);
  cast_param<<<16, 256, 0, stream>>>(d_in[16], pe2, 4096,  flag);

  cast_in<<<dim3((NTOK * EMBED) / 256), 256, 0, stream>>>(
      d_in[0], xf, xb, NTOK * EMBED, flag);

  for (int l = 0; l < 4; l++) {
    // convert this layer's weights to bf16 (Wq|Wk|Wv stacked = fused QKV W)
    cast_weights<<<6144, 256, 0, stream>>>(
        d_in[1], d_in[3], d_in[5], d_in[7], d_in[9], d_in[11],
        (size_t)l * 1048576, (size_t)l * 4194304, wbf, flag);

    gemm_qkv<<<dim3(32, 24), 256, 0, stream>>>(
        xb, wbf, pbq + l * 1024, pbk + l * 1024, pbv + l * 1024,
        q, kk, vv, EMBED);
    attn_band<<<dim3(SEQL / 32, 32), 256, 0, stream>>>(q, kk, vv, ao);
    // O-proj: split-K x2 -> partials in dead kk/vv (1024 blocks = 4/CU)
    gemm_bt<0, 64, 2><<<dim3(32, 16, 2), 256, 0, stream>>>(
        ao, wbf + 3 * 1048576, pbo + l * 1024, kk, vv, EMBED, EMBED);
    resid_ln<<<dim3(NTOK), 256, 0, stream>>>(
        xf, kk, vv, pg1 + l * 1024, pe1 + l * 1024, xf, xb, nullptr, flag);
    gemm_bt<1, 128, 1><<<dim3(32, 32, 1), 256, 0, stream>>>(
        xb, wbf + 4 * 1048576, pb1 + l * 4096, hh, nullptr, FF_DIM, EMBED);
    // FF2: split-K x2 -> partials in y + dead xb (1024 blocks = 4/CU)
    gemm_bt<0, 64, 2><<<dim3(32, 16, 2), 256, 0, stream>>>(
        hh, wbf + 8 * 1048576, pb2 + l * 1024, y, xb, EMBED, FF_DIM);
    resid_ln<<<dim3(NTOK), 256, 0, stream>>>(
        xf, y, xb, pg2 + l * 1024, pe2 + l * 1024, xf, xb,
        l == 3 ? d_out : nullptr, flag);
  }
}